// Round 9
// baseline (1635.225 us; speedup 1.0000x reference)
//
#include <hip/hip_runtime.h>
#include <hip/hip_bf16.h>
#include <math.h>

// WaveNet on MI355X — round 9: single persistent fused kernel.
// R8 still ~18us/layer and invisible under ws-fills. This round: all 18
// layers in ONE kernel; block owns 256 rows forever; producer-consumer
// flag sync (fwd: wb-1,wb-2 at layer l-1; bwd: wb+1,wb+2 at l-2 for the
// triple-buffered plane overwrite); skip accumulated in registers; swapped
// MFMA operands (C-col = time row) so each lane holds f/g for its own row
// -> no LDS transpose. launch_bounds(256,4) caps VGPR at 128 -> capacity
// 4 blocks/CU = 1024 = grid -> all blocks co-resident, no deadlock.

typedef __attribute__((ext_vector_type(8))) short short8;
typedef __attribute__((ext_vector_type(4))) unsigned short ushort4v;
typedef __attribute__((ext_vector_type(16))) float f32x16;

constexpr int TL = 65536;
constexpr int NTOT = 262144;
constexpr int NBLK = 1024;
constexpr size_t PLANE = 4194304;   // ushorts per plane (NTOT*16)

__device__ __forceinline__ unsigned short f2bf(float v) {
    __hip_bfloat16 b = __float2bfloat16(v);
    unsigned short u; __builtin_memcpy(&u, &b, 2); return u;
}
__device__ __forceinline__ float bf2f(unsigned int u) {
    unsigned int x = (u & 0xffffu) << 16;
    float f; __builtin_memcpy(&f, &x, 4); return f;
}
__device__ __forceinline__ float softsign_f(float v) {
    return v * __builtin_amdgcn_rcpf(1.0f + fabsf(v));
}
__device__ __forceinline__ void spin_on(const unsigned int* f) {
    while (__hip_atomic_load(f, __ATOMIC_RELAXED, __HIP_MEMORY_SCOPE_AGENT) == 0u) {
        __builtin_amdgcn_s_sleep(2);
    }
}

// ---------------- weight packing (same layout as R8) ----------------
__global__ __launch_bounds__(256) void pack_kernel(
    const float* __restrict__ start_w,
    const float* __restrict__ conv_w,
    const float* __restrict__ gate_w,
    const float* __restrict__ res_w,
    const float* __restrict__ conv_b,
    const float* __restrict__ gate_b,
    unsigned short* __restrict__ bfrag,
    float* __restrict__ fgbias,
    float* __restrict__ rwp,
    float* __restrict__ e0f, float* __restrict__ e0g)
{
    int idx = blockIdx.x * 256 + threadIdx.x;
    if (idx < 55296) {                       // 18*3*2*64*8
        int li = idx / 3072, r = idx % 3072;
        int tap = r / 1024, r2 = r % 1024;
        int p = r2 / 512, r3 = r2 % 512;
        int lane = r3 / 8, j = r3 % 8;
        int n = lane & 31, kh = lane >> 5;
        int i_ch = kh * 8 + j, o = n & 15;
        const float* src = (n < 16) ? conv_w : gate_w;
        float w = src[((li * 16 + o) * 16 + i_ch) * 3 + tap];
        unsigned short hi = f2bf(w);
        bfrag[idx] = (p == 0) ? hi : f2bf(w - bf2f(hi));
    } else if (idx < 55296 + 576) {
        int u = idx - 55296; int li = u / 32, n = u % 32;
        fgbias[u] = (n < 16) ? conv_b[li * 16 + n] : gate_b[li * 16 + n - 16];
    } else if (idx < 55296 + 576 + 4352) {
        int u = idx - 55872; int li = u / 256, r = u % 256, i = r / 16, o = r % 16;
        rwp[u] = res_w[(li * 16 + o) * 16 + i];
    } else if (idx < 60320) {
        int u = idx - 60224; int which = u / 48, r = u % 48, k = r / 16, o = r % 16;
        const float* src = which ? gate_w : conv_w;
        float s = 0.f;
        #pragma unroll
        for (int i = 0; i < 16; ++i) s += src[(o * 16 + i) * 3 + k] * start_w[i];
        (which ? e0g : e0f)[k * 16 + o] = s;
    }
}

// ---------------- persistent fused kernel ----------------
__global__ __launch_bounds__(256, 4) void wavenet_fused(
    const float* __restrict__ x,
    const float* __restrict__ start_w,
    const float* __restrict__ conv_b,
    const float* __restrict__ gate_b,
    const float* __restrict__ res_b,
    const float* __restrict__ mixer_w,
    const unsigned short* __restrict__ bfrag,
    const float* __restrict__ fgbias,
    const float* __restrict__ rwp,
    const float* __restrict__ e0f,
    const float* __restrict__ e0g,
    unsigned short* __restrict__ pbase,   // 3 plane-pairs (hi,lo)
    float* __restrict__ out,
    unsigned int* __restrict__ flags)     // [17][NBLK]
{
    __shared__ float rwl[256];
    __shared__ float sml[64];   // [0:16) mx  [16:32) rb  [32:64) fgbias

    const int td   = threadIdx.x;
    const int wid  = td >> 6;
    const int lane = td & 63;
    const int r0   = lane & 31;
    const int kh   = lane >> 5;
    const int wb   = ((int)blockIdx.x & 7) * (NBLK >> 3) + ((int)blockIdx.x >> 3);
    const int base = wb * 256;

    float skipreg[2];

    // ================= layer 0 (VALU, tiny) =================
    {
        unsigned short* h0 = pbase;
        unsigned short* l0 = pbase + PLANE;
        #pragma unroll
        for (int tile = 0; tile < 2; ++tile) {
            const int j = base + tile * 128 + wid * 32 + r0;
            const int t = j & (TL - 1);
            const float x2 = x[j];
            const float x1 = (t >= 1) ? x[j - 1] : 0.f;
            const float x0 = (t >= 2) ? x[j - 2] : 0.f;
            const float xs[3] = {x0, x1, x2};
            float fv[16], qv[16];
            #pragma unroll
            for (int o = 0; o < 16; ++o) { fv[o] = conv_b[o]; qv[o] = gate_b[o]; }
            #pragma unroll
            for (int k = 0; k < 3; ++k) {
                #pragma unroll
                for (int o = 0; o < 16; ++o) {
                    fv[o] += e0f[k * 16 + o] * xs[k];
                    qv[o] += e0g[k * 16 + o] * xs[k];
                }
            }
            float z[16];
            #pragma unroll
            for (int o = 0; o < 16; ++o) z[o] = softsign_f(fv[o]) * softsign_f(qv[o]);
            float s = 0.f;
            #pragma unroll
            for (int o = 0; o < 16; ++o) s += mixer_w[o] * z[o];
            skipreg[tile] = s;
            float hn[16];
            #pragma unroll
            for (int o = 0; o < 16; ++o) hn[o] = start_w[o] * x2 + res_b[o];
            #pragma unroll
            for (int i = 0; i < 16; ++i) {
                #pragma unroll
                for (int o = 0; o < 16; ++o) hn[o] += rwp[i * 16 + o] * z[i];
            }
            if (kh == 0) {
                short8 ph0, ph1, pl0, pl1;
                #pragma unroll
                for (int o = 0; o < 8; ++o) {
                    unsigned short u = f2bf(hn[o]);
                    ph0[o] = (short)u; pl0[o] = (short)f2bf(hn[o] - bf2f(u));
                    unsigned short v = f2bf(hn[8 + o]);
                    ph1[o] = (short)v; pl1[o] = (short)f2bf(hn[8 + o] - bf2f(v));
                }
                *(short8*)(h0 + (size_t)j * 16)     = ph0;
                *(short8*)(h0 + (size_t)j * 16 + 8) = ph1;
                *(short8*)(l0 + (size_t)j * 16)     = pl0;
                *(short8*)(l0 + (size_t)j * 16 + 8) = pl1;
            }
        }
    }
    __syncthreads();
    if (td == 0) {
        __threadfence();
        __hip_atomic_store(&flags[wb], 1u, __ATOMIC_RELAXED, __HIP_MEMORY_SCOPE_AGENT);
    }

    // ================= layers 1..17 (MFMA) =================
    for (int li = 1; li < 18; ++li) {
        const int d = 1 << (li < 9 ? li : li - 9);
        const unsigned short* hin_hi  = pbase + (size_t)((li - 1) % 3) * (2 * PLANE);
        const unsigned short* hin_lo  = hin_hi + PLANE;
        unsigned short* hout_hi = pbase + (size_t)(li % 3) * (2 * PLANE);
        unsigned short* hout_lo = hout_hi + PLANE;

        // stage per-layer smalls into LDS
        if (li < 17) rwl[td] = rwp[li * 256 + td];
        if (td < 16)      sml[td] = mixer_w[li * 16 + td];
        else if (td < 32) sml[td] = (li < 17) ? res_b[li * 16 + td - 16] : 0.f;
        else if (td < 64) sml[td] = fgbias[li * 32 + td - 32];

        // sync: fwd = data ready; bwd = plane safe to overwrite (lag 2)
        if (td == 0 && wb >= 1) spin_on(&flags[(li - 1) * NBLK + wb - 1]);
        if (td == 1 && wb >= 2) spin_on(&flags[(li - 1) * NBLK + wb - 2]);
        if (li >= 3 && li < 17) {
            if (td == 2 && wb + 1 < NBLK) spin_on(&flags[(li - 2) * NBLK + wb + 1]);
            if (td == 3 && wb + 2 < NBLK) spin_on(&flags[(li - 2) * NBLK + wb + 2]);
        }
        if (td < 4) __threadfence();
        __syncthreads();

        // weight fragments for this layer (reused across both tiles)
        const short8* bfp = (const short8*)(bfrag + li * 3072);
        const short8 bhi0 = bfp[0 * 64 + lane], blo0 = bfp[1 * 64 + lane];
        const short8 bhi1 = bfp[2 * 64 + lane], blo1 = bfp[3 * 64 + lane];
        const short8 bhi2 = bfp[4 * 64 + lane], blo2 = bfp[5 * 64 + lane];

        short8 zero8;
        #pragma unroll
        for (int e = 0; e < 8; ++e) zero8[e] = 0;

        #pragma unroll
        for (int tile = 0; tile < 2; ++tile) {
            const int j = base + tile * 128 + wid * 32 + r0;
            const int t = j & (TL - 1);

            short8 ahi[3], alo[3];
            #pragma unroll
            for (int k = 0; k < 3; ++k) {
                const int off = (k - 2) * d;
                const bool ok = (t + off) >= 0;
                const size_t bofs = (size_t)(ok ? (j + off) : j) * 16 + kh * 8;
                short8 h = *(const short8*)(hin_hi + bofs);
                short8 l = *(const short8*)(hin_lo + bofs);
                if (!ok) { h = zero8; l = zero8; }
                ahi[k] = h; alo[k] = l;
            }

            // bias init from LDS (C-row = o|o+16, col = time row)
            f32x16 acc;
            {
                float4 b0 = *(float4*)&sml[32 + 4 * kh];
                float4 b1 = *(float4*)&sml[40 + 4 * kh];
                float4 b2 = *(float4*)&sml[48 + 4 * kh];
                float4 b3 = *(float4*)&sml[56 + 4 * kh];
                acc[0]=b0.x; acc[1]=b0.y; acc[2]=b0.z; acc[3]=b0.w;
                acc[4]=b1.x; acc[5]=b1.y; acc[6]=b1.z; acc[7]=b1.w;
                acc[8]=b2.x; acc[9]=b2.y; acc[10]=b2.z; acc[11]=b2.w;
                acc[12]=b3.x; acc[13]=b3.y; acc[14]=b3.z; acc[15]=b3.w;
            }
            acc = __builtin_amdgcn_mfma_f32_32x32x16_bf16(bhi0, ahi[0], acc, 0, 0, 0);
            acc = __builtin_amdgcn_mfma_f32_32x32x16_bf16(blo0, ahi[0], acc, 0, 0, 0);
            acc = __builtin_amdgcn_mfma_f32_32x32x16_bf16(bhi0, alo[0], acc, 0, 0, 0);
            acc = __builtin_amdgcn_mfma_f32_32x32x16_bf16(bhi1, ahi[1], acc, 0, 0, 0);
            acc = __builtin_amdgcn_mfma_f32_32x32x16_bf16(blo1, ahi[1], acc, 0, 0, 0);
            acc = __builtin_amdgcn_mfma_f32_32x32x16_bf16(bhi1, alo[1], acc, 0, 0, 0);
            acc = __builtin_amdgcn_mfma_f32_32x32x16_bf16(bhi2, ahi[2], acc, 0, 0, 0);
            acc = __builtin_amdgcn_mfma_f32_32x32x16_bf16(blo2, ahi[2], acc, 0, 0, 0);
            acc = __builtin_amdgcn_mfma_f32_32x32x16_bf16(bhi2, alo[2], acc, 0, 0, 0);

            // z for this lane's 8 channels: o = (r&3)+8*(r>>2)+4*kh
            float z8[8];
            #pragma unroll
            for (int r = 0; r < 8; ++r)
                z8[r] = softsign_f(acc[r]) * softsign_f(acc[r + 8]);

            float4 m0 = *(float4*)&sml[4 * kh];
            float4 m1 = *(float4*)&sml[8 + 4 * kh];
            float part = m0.x*z8[0] + m0.y*z8[1] + m0.z*z8[2] + m0.w*z8[3]
                       + m1.x*z8[4] + m1.y*z8[5] + m1.z*z8[6] + m1.w*z8[7];
            float tot = part + __shfl_xor(part, 32);

            if (li == 17) {
                if (kh == 0) out[j] = skipreg[tile] + tot;
            } else {
                if (kh == 0) skipreg[tile] += tot;

                float zo8[8];
                #pragma unroll
                for (int r = 0; r < 8; ++r) zo8[r] = __shfl_xor(z8[r], 32);

                // h(t) channels regrouped to this lane's o-set via shfl
                unsigned int uh[4], ul[4];
                __builtin_memcpy(uh, &ahi[2], 16);
                __builtin_memcpy(ul, &alo[2], 16);
                unsigned int sh0 = kh ? uh[0] : uh[2], sh1 = kh ? uh[1] : uh[3];
                unsigned int sl0 = kh ? ul[0] : ul[2], sl1 = kh ? ul[1] : ul[3];
                unsigned int rh0 = (unsigned int)__shfl_xor((int)sh0, 32);
                unsigned int rh1 = (unsigned int)__shfl_xor((int)sh1, 32);
                unsigned int rl0 = (unsigned int)__shfl_xor((int)sl0, 32);
                unsigned int rl1 = (unsigned int)__shfl_xor((int)sl1, 32);
                unsigned int qh0 = kh ? uh[2] : uh[0], qh1 = kh ? uh[3] : uh[1];
                unsigned int ql0 = kh ? ul[2] : ul[0], ql1 = kh ? ul[3] : ul[1];
                unsigned int g1h0 = kh ? rh0 : qh0, g1h1 = kh ? rh1 : qh1;
                unsigned int g2h0 = kh ? qh0 : rh0, g2h1 = kh ? qh1 : rh1;
                unsigned int g1l0 = kh ? rl0 : ql0, g1l1 = kh ? rl1 : ql1;
                unsigned int g2l0 = kh ? ql0 : rl0, g2l1 = kh ? ql1 : rl1;

                float4 rb0 = *(float4*)&sml[16 + 4 * kh];
                float4 rb1 = *(float4*)&sml[24 + 4 * kh];
                float hn[8];
                hn[0] = bf2f(g1h0) + bf2f(g1l0) + rb0.x;
                hn[1] = bf2f(g1h0 >> 16) + bf2f(g1l0 >> 16) + rb0.y;
                hn[2] = bf2f(g1h1) + bf2f(g1l1) + rb0.z;
                hn[3] = bf2f(g1h1 >> 16) + bf2f(g1l1 >> 16) + rb0.w;
                hn[4] = bf2f(g2h0) + bf2f(g2l0) + rb1.x;
                hn[5] = bf2f(g2h0 >> 16) + bf2f(g2l0 >> 16) + rb1.y;
                hn[6] = bf2f(g2h1) + bf2f(g2l1) + rb1.z;
                hn[7] = bf2f(g2h1 >> 16) + bf2f(g2l1 >> 16) + rb1.w;

                #pragma unroll
                for (int i = 0; i < 16; ++i) {
                    const int idx = (i & 3) + 4 * (i >> 3);
                    const int ob  = (i >> 2) & 1;
                    const float zi = (ob == kh) ? z8[idx] : zo8[idx];
                    float4 wA = *(float4*)&rwl[i * 16 + 4 * kh];
                    float4 wB = *(float4*)&rwl[i * 16 + 8 + 4 * kh];
                    hn[0] += wA.x * zi; hn[1] += wA.y * zi;
                    hn[2] += wA.z * zi; hn[3] += wA.w * zi;
                    hn[4] += wB.x * zi; hn[5] += wB.y * zi;
                    hn[6] += wB.z * zi; hn[7] += wB.w * zi;
                }

                ushort4v p1h, p2h, p1l, p2l;
                #pragma unroll
                for (int m = 0; m < 4; ++m) {
                    unsigned short u1 = f2bf(hn[m]);
                    p1h[m] = u1; p1l[m] = f2bf(hn[m] - bf2f(u1));
                    unsigned short u2 = f2bf(hn[4 + m]);
                    p2h[m] = u2; p2l[m] = f2bf(hn[4 + m] - bf2f(u2));
                }
                *(ushort4v*)(hout_hi + (size_t)j * 16 + 4 * kh)     = p1h;
                *(ushort4v*)(hout_hi + (size_t)j * 16 + 8 + 4 * kh) = p2h;
                *(ushort4v*)(hout_lo + (size_t)j * 16 + 4 * kh)     = p1l;
                *(ushort4v*)(hout_lo + (size_t)j * 16 + 8 + 4 * kh) = p2l;
            }
        }

        if (li < 17) {
            __syncthreads();
            if (td == 0) {
                __threadfence();
                __hip_atomic_store(&flags[li * NBLK + wb], 1u,
                                   __ATOMIC_RELAXED, __HIP_MEMORY_SCOPE_AGENT);
            }
        }
    }
}

extern "C" void kernel_launch(void* const* d_in, const int* in_sizes, int n_in,
                              void* d_out, int out_size, void* d_ws, size_t ws_size,
                              hipStream_t stream) {
    const float* x       = (const float*)d_in[0];
    const float* start_w = (const float*)d_in[1];
    const float* conv_w  = (const float*)d_in[2];
    const float* conv_b  = (const float*)d_in[3];
    const float* gate_w  = (const float*)d_in[4];
    const float* gate_b  = (const float*)d_in[5];
    const float* res_w   = (const float*)d_in[6];
    const float* res_b   = (const float*)d_in[7];
    const float* mixer_w = (const float*)d_in[8];
    float* out = (float*)d_out;

    float* ws = (float*)d_ws;
    unsigned short* bfrag = (unsigned short*)ws;            // 55296 ushorts
    float* fgbias = ws + 27648;                             // 576
    float* rwp    = fgbias + 576;                           // 4352
    float* e0f    = rwp + 4352;                             // 48
    float* e0g    = e0f + 48;                               // 48
    unsigned short* pbase = (unsigned short*)(e0g + 48);    // 3 plane-pairs
    unsigned int* flags = (unsigned int*)(pbase + 6 * PLANE); // 17*1024
    (void)ws_size; (void)in_sizes; (void)n_in; (void)out_size;

    hipMemsetAsync(flags, 0, 17 * NBLK * sizeof(unsigned int), stream);

    pack_kernel<<<236, 256, 0, stream>>>(start_w, conv_w, gate_w, res_w,
                                         conv_b, gate_b,
                                         bfrag, fgbias, rwp, e0f, e0g);

    wavenet_fused<<<NBLK, 256, 0, stream>>>(
        x, start_w, conv_b, gate_b, res_b, mixer_w,
        bfrag, fgbias, rwp, e0f, e0g, pbase, out, flags);
}

// Round 10
// 1442.460 us; speedup vs baseline: 1.1336x; 1.1336x over previous
//
#include <hip/hip_runtime.h>
#include <hip/hip_bf16.h>
#include <math.h>

// WaveNet on MI355X — round 10: fused persistent kernel, spill-free by
// construction. R9 forensics: allocator chose 64 VGPRs (5th time it ignored
// occupancy hints) vs ~105 live -> 26 floats/thread/layer spilled (WRITE
// excess 460MB), 1635us. Fix: shrink liveness under 64 arch VGPRs:
//  - taps serialized (#pragma unroll 1): one (ahi,alo) pair live;
//  - b-fragments loaded per-k (8 regs), L2-hot;
//  - 2 buffer sets (lag-1 backward wait) -> 32MB h, ~L2-resident.
// Everything else (flag sync, reg-resident skip, swapped-operand MFMA,
// epilogue regroup) carried from R9 which passed correctness.

typedef __attribute__((ext_vector_type(8))) short short8;
typedef __attribute__((ext_vector_type(4))) unsigned short ushort4v;
typedef __attribute__((ext_vector_type(16))) float f32x16;

constexpr int TL = 65536;
constexpr int NTOT = 262144;
constexpr int NBLK = 1024;
constexpr size_t PLANE = 4194304;   // ushorts per plane (NTOT*16)

__device__ __forceinline__ unsigned short f2bf(float v) {
    __hip_bfloat16 b = __float2bfloat16(v);
    unsigned short u; __builtin_memcpy(&u, &b, 2); return u;
}
__device__ __forceinline__ float bf2f(unsigned int u) {
    unsigned int x = (u & 0xffffu) << 16;
    float f; __builtin_memcpy(&f, &x, 4); return f;
}
__device__ __forceinline__ float softsign_f(float v) {
    return v * __builtin_amdgcn_rcpf(1.0f + fabsf(v));
}
__device__ __forceinline__ void spin_on(const unsigned int* f) {
    while (__hip_atomic_load(f, __ATOMIC_RELAXED, __HIP_MEMORY_SCOPE_AGENT) == 0u) {
        __builtin_amdgcn_s_sleep(2);
    }
}

// ---------------- weight packing (same layout as R8/R9) ----------------
__global__ __launch_bounds__(256) void pack_kernel(
    const float* __restrict__ start_w,
    const float* __restrict__ conv_w,
    const float* __restrict__ gate_w,
    const float* __restrict__ res_w,
    const float* __restrict__ conv_b,
    const float* __restrict__ gate_b,
    unsigned short* __restrict__ bfrag,
    float* __restrict__ fgbias,
    float* __restrict__ rwp,
    float* __restrict__ e0f, float* __restrict__ e0g)
{
    int idx = blockIdx.x * 256 + threadIdx.x;
    if (idx < 55296) {                       // 18*3*2*64*8
        int li = idx / 3072, r = idx % 3072;
        int tap = r / 1024, r2 = r % 1024;
        int p = r2 / 512, r3 = r2 % 512;
        int lane = r3 / 8, j = r3 % 8;
        int n = lane & 31, kh = lane >> 5;
        int i_ch = kh * 8 + j, o = n & 15;
        const float* src = (n < 16) ? conv_w : gate_w;
        float w = src[((li * 16 + o) * 16 + i_ch) * 3 + tap];
        unsigned short hi = f2bf(w);
        bfrag[idx] = (p == 0) ? hi : f2bf(w - bf2f(hi));
    } else if (idx < 55296 + 576) {
        int u = idx - 55296; int li = u / 32, n = u % 32;
        fgbias[u] = (n < 16) ? conv_b[li * 16 + n] : gate_b[li * 16 + n - 16];
    } else if (idx < 55296 + 576 + 4352) {
        int u = idx - 55872; int li = u / 256, r = u % 256, i = r / 16, o = r % 16;
        rwp[u] = res_w[(li * 16 + o) * 16 + i];
    } else if (idx < 60320) {
        int u = idx - 60224; int which = u / 48, r = u % 48, k = r / 16, o = r % 16;
        const float* src = which ? gate_w : conv_w;
        float s = 0.f;
        #pragma unroll
        for (int i = 0; i < 16; ++i) s += src[(o * 16 + i) * 3 + k] * start_w[i];
        (which ? e0g : e0f)[k * 16 + o] = s;
    }
}

// ---------------- persistent fused kernel ----------------
__global__ __launch_bounds__(256, 4) void wavenet_fused(
    const float* __restrict__ x,
    const float* __restrict__ start_w,
    const float* __restrict__ conv_b,
    const float* __restrict__ gate_b,
    const float* __restrict__ res_b,
    const float* __restrict__ mixer_w,
    const unsigned short* __restrict__ bfrag,
    const float* __restrict__ fgbias,
    const float* __restrict__ rwp,
    const float* __restrict__ e0f,
    const float* __restrict__ e0g,
    unsigned short* __restrict__ pbase,   // 2 plane-pairs (hi,lo)
    float* __restrict__ out,
    unsigned int* __restrict__ flags)     // [17][NBLK]
{
    __shared__ float rwl[256];
    __shared__ float sml[64];   // [0:16) mx  [16:32) rb  [32:64) fgbias

    const int td   = threadIdx.x;
    const int wid  = td >> 6;
    const int lane = td & 63;
    const int r0   = lane & 31;
    const int kh   = lane >> 5;
    const int wb   = ((int)blockIdx.x & 7) * (NBLK >> 3) + ((int)blockIdx.x >> 3);
    const int base = wb * 256;

    float skipreg[2];

    // ================= layer 0 (VALU, tiny) =================
    {
        unsigned short* h0 = pbase;
        unsigned short* l0 = pbase + PLANE;
        #pragma unroll
        for (int tile = 0; tile < 2; ++tile) {
            const int j = base + tile * 128 + wid * 32 + r0;
            const int t = j & (TL - 1);
            const float x2 = x[j];
            const float x1 = (t >= 1) ? x[j - 1] : 0.f;
            const float x0 = (t >= 2) ? x[j - 2] : 0.f;
            const float xs[3] = {x0, x1, x2};
            float fv[16], qv[16];
            #pragma unroll
            for (int o = 0; o < 16; ++o) { fv[o] = conv_b[o]; qv[o] = gate_b[o]; }
            #pragma unroll
            for (int k = 0; k < 3; ++k) {
                #pragma unroll
                for (int o = 0; o < 16; ++o) {
                    fv[o] += e0f[k * 16 + o] * xs[k];
                    qv[o] += e0g[k * 16 + o] * xs[k];
                }
            }
            float z[16];
            #pragma unroll
            for (int o = 0; o < 16; ++o) z[o] = softsign_f(fv[o]) * softsign_f(qv[o]);
            float s = 0.f;
            #pragma unroll
            for (int o = 0; o < 16; ++o) s += mixer_w[o] * z[o];
            skipreg[tile] = s;
            float hn[16];
            #pragma unroll
            for (int o = 0; o < 16; ++o) hn[o] = start_w[o] * x2 + res_b[o];
            #pragma unroll
            for (int i = 0; i < 16; ++i) {
                #pragma unroll
                for (int o = 0; o < 16; ++o) hn[o] += rwp[i * 16 + o] * z[i];
            }
            if (kh == 0) {
                short8 ph0, ph1, pl0, pl1;
                #pragma unroll
                for (int o = 0; o < 8; ++o) {
                    unsigned short u = f2bf(hn[o]);
                    ph0[o] = (short)u; pl0[o] = (short)f2bf(hn[o] - bf2f(u));
                    unsigned short v = f2bf(hn[8 + o]);
                    ph1[o] = (short)v; pl1[o] = (short)f2bf(hn[8 + o] - bf2f(v));
                }
                *(short8*)(h0 + (size_t)j * 16)     = ph0;
                *(short8*)(h0 + (size_t)j * 16 + 8) = ph1;
                *(short8*)(l0 + (size_t)j * 16)     = pl0;
                *(short8*)(l0 + (size_t)j * 16 + 8) = pl1;
            }
        }
    }
    __syncthreads();
    if (td == 0) {
        __threadfence();
        __hip_atomic_store(&flags[wb], 1u, __ATOMIC_RELAXED, __HIP_MEMORY_SCOPE_AGENT);
    }

    // ================= layers 1..17 (MFMA) =================
    for (int li = 1; li < 18; ++li) {
        const int d = 1 << (li < 9 ? li : li - 9);
        // 2 buffer sets: read (li-1)&1, write li&1
        const unsigned short* hin_hi = pbase + (size_t)((li - 1) & 1) * (2 * PLANE);
        const unsigned short* hin_lo = hin_hi + PLANE;
        unsigned short* hout_hi = pbase + (size_t)(li & 1) * (2 * PLANE);
        unsigned short* hout_lo = hout_hi + PLANE;

        // stage per-layer smalls into LDS
        if (li < 17) rwl[td] = rwp[li * 256 + td];
        if (td < 16)      sml[td] = mixer_w[li * 16 + td];
        else if (td < 32) sml[td] = (li < 17) ? res_b[li * 16 + td - 16] : 0.f;
        else if (td < 64) sml[td] = fgbias[li * 32 + td - 32];

        // waits at level li-1: fwd wb-1,wb-2 (data ready), bwd wb+1,wb+2
        // (their reads of the set we are about to overwrite are done)
        if (td == 0 && wb >= 1) spin_on(&flags[(li - 1) * NBLK + wb - 1]);
        if (td == 1 && wb >= 2) spin_on(&flags[(li - 1) * NBLK + wb - 2]);
        if (td == 2 && wb + 1 < NBLK) spin_on(&flags[(li - 1) * NBLK + wb + 1]);
        if (td == 3 && wb + 2 < NBLK) spin_on(&flags[(li - 1) * NBLK + wb + 2]);
        if (td < 4) __threadfence();
        __syncthreads();

        const short8* bfp = (const short8*)(bfrag + li * 3072);
        short8 zero8;
        #pragma unroll
        for (int e = 0; e < 8; ++e) zero8[e] = 0;

        #pragma unroll
        for (int tile = 0; tile < 2; ++tile) {
            const int j = base + tile * 128 + wid * 32 + r0;
            const int t = j & (TL - 1);

            // bias init (C-row = channel, col = time row)
            f32x16 acc;
            {
                float4 b0 = *(float4*)&sml[32 + 4 * kh];
                float4 b1 = *(float4*)&sml[40 + 4 * kh];
                float4 b2 = *(float4*)&sml[48 + 4 * kh];
                float4 b3 = *(float4*)&sml[56 + 4 * kh];
                acc[0]=b0.x; acc[1]=b0.y; acc[2]=b0.z; acc[3]=b0.w;
                acc[4]=b1.x; acc[5]=b1.y; acc[6]=b1.z; acc[7]=b1.w;
                acc[8]=b2.x; acc[9]=b2.y; acc[10]=b2.z; acc[11]=b2.w;
                acc[12]=b3.x; acc[13]=b3.y; acc[14]=b3.z; acc[15]=b3.w;
            }

            // serial taps: one (ah,al) + one (bh,bl) live at a time.
            short8 ah, al;
            #pragma unroll 1
            for (int k = 0; k < 3; ++k) {
                const int off = (k - 2) * d;
                const bool ok = (t + off) >= 0;
                const size_t bofs = (size_t)(ok ? (j + off) : j) * 16 + kh * 8;
                ah = *(const short8*)(hin_hi + bofs);
                al = *(const short8*)(hin_lo + bofs);
                if (!ok) { ah = zero8; al = zero8; }
                short8 bh = bfp[(k * 2 + 0) * 64 + lane];
                short8 bl = bfp[(k * 2 + 1) * 64 + lane];
                acc = __builtin_amdgcn_mfma_f32_32x32x16_bf16(bh, ah, acc, 0, 0, 0);
                acc = __builtin_amdgcn_mfma_f32_32x32x16_bf16(bl, ah, acc, 0, 0, 0);
                acc = __builtin_amdgcn_mfma_f32_32x32x16_bf16(bh, al, acc, 0, 0, 0);
            }
            // ah/al now hold tap k=2 (= h at t), used by the residual below.

            float z8[8];
            #pragma unroll
            for (int r = 0; r < 8; ++r)
                z8[r] = softsign_f(acc[r]) * softsign_f(acc[r + 8]);

            float4 m0 = *(float4*)&sml[4 * kh];
            float4 m1 = *(float4*)&sml[8 + 4 * kh];
            float part = m0.x*z8[0] + m0.y*z8[1] + m0.z*z8[2] + m0.w*z8[3]
                       + m1.x*z8[4] + m1.y*z8[5] + m1.z*z8[6] + m1.w*z8[7];
            float tot = part + __shfl_xor(part, 32);

            if (li == 17) {
                if (kh == 0) out[j] = skipreg[tile] + tot;
            } else {
                if (kh == 0) skipreg[tile] += tot;

                float zo8[8];
                #pragma unroll
                for (int r = 0; r < 8; ++r) zo8[r] = __shfl_xor(z8[r], 32);

                // h(t) channels regrouped to this lane's o-set via shfl
                unsigned int uh[4], ul[4];
                __builtin_memcpy(uh, &ah, 16);
                __builtin_memcpy(ul, &al, 16);
                unsigned int sh0 = kh ? uh[0] : uh[2], sh1 = kh ? uh[1] : uh[3];
                unsigned int sl0 = kh ? ul[0] : ul[2], sl1 = kh ? ul[1] : ul[3];
                unsigned int rh0 = (unsigned int)__shfl_xor((int)sh0, 32);
                unsigned int rh1 = (unsigned int)__shfl_xor((int)sh1, 32);
                unsigned int rl0 = (unsigned int)__shfl_xor((int)sl0, 32);
                unsigned int rl1 = (unsigned int)__shfl_xor((int)sl1, 32);
                unsigned int qh0 = kh ? uh[2] : uh[0], qh1 = kh ? uh[3] : uh[1];
                unsigned int ql0 = kh ? ul[2] : ul[0], ql1 = kh ? ul[3] : ul[1];
                unsigned int g1h0 = kh ? rh0 : qh0, g1h1 = kh ? rh1 : qh1;
                unsigned int g2h0 = kh ? qh0 : rh0, g2h1 = kh ? qh1 : rh1;
                unsigned int g1l0 = kh ? rl0 : ql0, g1l1 = kh ? rl1 : ql1;
                unsigned int g2l0 = kh ? ql0 : rl0, g2l1 = kh ? ql1 : rl1;

                float4 rb0 = *(float4*)&sml[16 + 4 * kh];
                float4 rb1 = *(float4*)&sml[24 + 4 * kh];
                float hn[8];
                hn[0] = bf2f(g1h0) + bf2f(g1l0) + rb0.x;
                hn[1] = bf2f(g1h0 >> 16) + bf2f(g1l0 >> 16) + rb0.y;
                hn[2] = bf2f(g1h1) + bf2f(g1l1) + rb0.z;
                hn[3] = bf2f(g1h1 >> 16) + bf2f(g1l1 >> 16) + rb0.w;
                hn[4] = bf2f(g2h0) + bf2f(g2l0) + rb1.x;
                hn[5] = bf2f(g2h0 >> 16) + bf2f(g2l0 >> 16) + rb1.y;
                hn[6] = bf2f(g2h1) + bf2f(g2l1) + rb1.z;
                hn[7] = bf2f(g2h1 >> 16) + bf2f(g2l1 >> 16) + rb1.w;

                #pragma unroll
                for (int i = 0; i < 16; ++i) {
                    const int idx = (i & 3) + 4 * (i >> 3);
                    const int ob  = (i >> 2) & 1;
                    const float zi = (ob == kh) ? z8[idx] : zo8[idx];
                    float4 wA = *(float4*)&rwl[i * 16 + 4 * kh];
                    float4 wB = *(float4*)&rwl[i * 16 + 8 + 4 * kh];
                    hn[0] += wA.x * zi; hn[1] += wA.y * zi;
                    hn[2] += wA.z * zi; hn[3] += wA.w * zi;
                    hn[4] += wB.x * zi; hn[5] += wB.y * zi;
                    hn[6] += wB.z * zi; hn[7] += wB.w * zi;
                }

                ushort4v p1h, p2h, p1l, p2l;
                #pragma unroll
                for (int m = 0; m < 4; ++m) {
                    unsigned short u1 = f2bf(hn[m]);
                    p1h[m] = u1; p1l[m] = f2bf(hn[m] - bf2f(u1));
                    unsigned short u2 = f2bf(hn[4 + m]);
                    p2h[m] = u2; p2l[m] = f2bf(hn[4 + m] - bf2f(u2));
                }
                *(ushort4v*)(hout_hi + (size_t)j * 16 + 4 * kh)     = p1h;
                *(ushort4v*)(hout_hi + (size_t)j * 16 + 8 + 4 * kh) = p2h;
                *(ushort4v*)(hout_lo + (size_t)j * 16 + 4 * kh)     = p1l;
                *(ushort4v*)(hout_lo + (size_t)j * 16 + 8 + 4 * kh) = p2l;
            }
        }

        if (li < 17) {
            __syncthreads();
            if (td == 0) {
                __threadfence();
                __hip_atomic_store(&flags[li * NBLK + wb], 1u,
                                   __ATOMIC_RELAXED, __HIP_MEMORY_SCOPE_AGENT);
            }
        }
    }
}

extern "C" void kernel_launch(void* const* d_in, const int* in_sizes, int n_in,
                              void* d_out, int out_size, void* d_ws, size_t ws_size,
                              hipStream_t stream) {
    const float* x       = (const float*)d_in[0];
    const float* start_w = (const float*)d_in[1];
    const float* conv_w  = (const float*)d_in[2];
    const float* conv_b  = (const float*)d_in[3];
    const float* gate_w  = (const float*)d_in[4];
    const float* gate_b  = (const float*)d_in[5];
    const float* res_w   = (const float*)d_in[6];
    const float* res_b   = (const float*)d_in[7];
    const float* mixer_w = (const float*)d_in[8];
    float* out = (float*)d_out;

    float* ws = (float*)d_ws;
    unsigned short* bfrag = (unsigned short*)ws;            // 55296 ushorts
    float* fgbias = ws + 27648;                             // 576
    float* rwp    = fgbias + 576;                           // 4352
    float* e0f    = rwp + 4352;                             // 48
    float* e0g    = e0f + 48;                               // 48
    unsigned short* pbase = (unsigned short*)(e0g + 48);    // 2 plane-pairs
    unsigned int* flags = (unsigned int*)(pbase + 4 * PLANE); // 17*1024
    (void)ws_size; (void)in_sizes; (void)n_in; (void)out_size;

    hipMemsetAsync(flags, 0, 17 * NBLK * sizeof(unsigned int), stream);

    pack_kernel<<<236, 256, 0, stream>>>(start_w, conv_w, gate_w, res_w,
                                         conv_b, gate_b,
                                         bfrag, fgbias, rwp, e0f, e0g);

    wavenet_fused<<<NBLK, 256, 0, stream>>>(
        x, start_w, conv_b, gate_b, res_b, mixer_w,
        bfrag, fgbias, rwp, e0f, e0g, pbase, out, flags);
}

// Round 11
// 370.524 us; speedup vs baseline: 4.4133x; 3.8930x over previous
//
#include <hip/hip_runtime.h>
#include <hip/hip_bf16.h>
#include <math.h>

// WaveNet on MI355X — round 11: fused persistent kernel, per-access coherence.
// R10 forensics: compute content ~90us but dur 1442us; __threadfence() (bulk
// L2 writeback+invalidate, agent scope) x 1024 blocks x 17 layers kept every
// XCD's L2 permanently cold -> all reads at L3 latency, 5% VALU util.
// Fix: h planes accessed ONLY via 8-byte agent-scope RELAXED atomics (per-
// instruction coherent, straight to L3; no bulk flush; weights stay L2-hot).
// Fences deleted: __syncthreads() drains vmcnt pre-barrier (m97) => h stores
// complete at L3 before the flag store; consumer tap loads are coherent and
// control-dependent on the spin. Spin backoff s_sleep(8).

typedef __attribute__((ext_vector_type(8))) short short8;
typedef __attribute__((ext_vector_type(4))) unsigned short ushort4v;
typedef __attribute__((ext_vector_type(16))) float f32x16;
typedef unsigned long long u64;

constexpr int TL = 65536;
constexpr int NTOT = 262144;
constexpr int NBLK = 1024;
constexpr size_t PLANE = 4194304;   // ushorts per plane (NTOT*16)

__device__ __forceinline__ unsigned short f2bf(float v) {
    __hip_bfloat16 b = __float2bfloat16(v);
    unsigned short u; __builtin_memcpy(&u, &b, 2); return u;
}
__device__ __forceinline__ float bf2f(unsigned int u) {
    unsigned int x = (u & 0xffffu) << 16;
    float f; __builtin_memcpy(&f, &x, 4); return f;
}
__device__ __forceinline__ float softsign_f(float v) {
    return v * __builtin_amdgcn_rcpf(1.0f + fabsf(v));
}
__device__ __forceinline__ void spin_on(const unsigned int* f) {
    while (__hip_atomic_load((unsigned int*)f, __ATOMIC_RELAXED,
                             __HIP_MEMORY_SCOPE_AGENT) == 0u) {
        __builtin_amdgcn_s_sleep(8);
    }
}
__device__ __forceinline__ u64 cohload(const unsigned short* p) {
    return __hip_atomic_load((u64*)p, __ATOMIC_RELAXED, __HIP_MEMORY_SCOPE_AGENT);
}
__device__ __forceinline__ void cohstore(unsigned short* p, u64 v) {
    __hip_atomic_store((u64*)p, v, __ATOMIC_RELAXED, __HIP_MEMORY_SCOPE_AGENT);
}

// ---------------- weight packing (same layout as R8-R10) ----------------
__global__ __launch_bounds__(256) void pack_kernel(
    const float* __restrict__ start_w,
    const float* __restrict__ conv_w,
    const float* __restrict__ gate_w,
    const float* __restrict__ res_w,
    const float* __restrict__ conv_b,
    const float* __restrict__ gate_b,
    unsigned short* __restrict__ bfrag,
    float* __restrict__ fgbias,
    float* __restrict__ rwp,
    float* __restrict__ e0f, float* __restrict__ e0g)
{
    int idx = blockIdx.x * 256 + threadIdx.x;
    if (idx < 55296) {                       // 18*3*2*64*8
        int li = idx / 3072, r = idx % 3072;
        int tap = r / 1024, r2 = r % 1024;
        int p = r2 / 512, r3 = r2 % 512;
        int lane = r3 / 8, j = r3 % 8;
        int n = lane & 31, kh = lane >> 5;
        int i_ch = kh * 8 + j, o = n & 15;
        const float* src = (n < 16) ? conv_w : gate_w;
        float w = src[((li * 16 + o) * 16 + i_ch) * 3 + tap];
        unsigned short hi = f2bf(w);
        bfrag[idx] = (p == 0) ? hi : f2bf(w - bf2f(hi));
    } else if (idx < 55296 + 576) {
        int u = idx - 55296; int li = u / 32, n = u % 32;
        fgbias[u] = (n < 16) ? conv_b[li * 16 + n] : gate_b[li * 16 + n - 16];
    } else if (idx < 55296 + 576 + 4352) {
        int u = idx - 55872; int li = u / 256, r = u % 256, i = r / 16, o = r % 16;
        rwp[u] = res_w[(li * 16 + o) * 16 + i];
    } else if (idx < 60320) {
        int u = idx - 60224; int which = u / 48, r = u % 48, k = r / 16, o = r % 16;
        const float* src = which ? gate_w : conv_w;
        float s = 0.f;
        #pragma unroll
        for (int i = 0; i < 16; ++i) s += src[(o * 16 + i) * 3 + k] * start_w[i];
        (which ? e0g : e0f)[k * 16 + o] = s;
    }
}

// ---------------- persistent fused kernel ----------------
__global__ __launch_bounds__(256, 4) void wavenet_fused(
    const float* __restrict__ x,
    const float* __restrict__ start_w,
    const float* __restrict__ conv_b,
    const float* __restrict__ gate_b,
    const float* __restrict__ res_b,
    const float* __restrict__ mixer_w,
    const unsigned short* __restrict__ bfrag,
    const float* __restrict__ fgbias,
    const float* __restrict__ rwp,
    const float* __restrict__ e0f,
    const float* __restrict__ e0g,
    unsigned short* __restrict__ pbase,   // 2 plane-pairs (hi,lo)
    float* __restrict__ out,
    unsigned int* __restrict__ flags)     // [17][NBLK]
{
    __shared__ float rwl[256];
    __shared__ float sml[64];   // [0:16) mx  [16:32) rb  [32:64) fgbias

    const int td   = threadIdx.x;
    const int wid  = td >> 6;
    const int lane = td & 63;
    const int r0   = lane & 31;
    const int kh   = lane >> 5;
    const int wb   = ((int)blockIdx.x & 7) * (NBLK >> 3) + ((int)blockIdx.x >> 3);
    const int base = wb * 256;

    float skipreg[2];

    // ================= layer 0 (VALU, tiny) =================
    {
        unsigned short* h0 = pbase;
        unsigned short* l0 = pbase + PLANE;
        #pragma unroll
        for (int tile = 0; tile < 2; ++tile) {
            const int j = base + tile * 128 + wid * 32 + r0;
            const int t = j & (TL - 1);
            const float x2 = x[j];
            const float x1 = (t >= 1) ? x[j - 1] : 0.f;
            const float x0 = (t >= 2) ? x[j - 2] : 0.f;
            const float xs[3] = {x0, x1, x2};
            float fv[16], qv[16];
            #pragma unroll
            for (int o = 0; o < 16; ++o) { fv[o] = conv_b[o]; qv[o] = gate_b[o]; }
            #pragma unroll
            for (int k = 0; k < 3; ++k) {
                #pragma unroll
                for (int o = 0; o < 16; ++o) {
                    fv[o] += e0f[k * 16 + o] * xs[k];
                    qv[o] += e0g[k * 16 + o] * xs[k];
                }
            }
            float z[16];
            #pragma unroll
            for (int o = 0; o < 16; ++o) z[o] = softsign_f(fv[o]) * softsign_f(qv[o]);
            float s = 0.f;
            #pragma unroll
            for (int o = 0; o < 16; ++o) s += mixer_w[o] * z[o];
            skipreg[tile] = s;
            float hn[16];
            #pragma unroll
            for (int o = 0; o < 16; ++o) hn[o] = start_w[o] * x2 + res_b[o];
            #pragma unroll
            for (int i = 0; i < 16; ++i) {
                #pragma unroll
                for (int o = 0; o < 16; ++o) hn[o] += rwp[i * 16 + o] * z[i];
            }
            if (kh == 0) {
                short8 ph, pl;
                #pragma unroll
                for (int o = 0; o < 8; ++o) {
                    unsigned short u = f2bf(hn[o]);
                    ph[o] = (short)u; pl[o] = (short)f2bf(hn[o] - bf2f(u));
                }
                short8 ph1, pl1;
                #pragma unroll
                for (int o = 0; o < 8; ++o) {
                    unsigned short v = f2bf(hn[8 + o]);
                    ph1[o] = (short)v; pl1[o] = (short)f2bf(hn[8 + o] - bf2f(v));
                }
                u64 w0[2], w1[2], w2[2], w3[2];
                __builtin_memcpy(w0, &ph, 16);
                __builtin_memcpy(w1, &ph1, 16);
                __builtin_memcpy(w2, &pl, 16);
                __builtin_memcpy(w3, &pl1, 16);
                cohstore(h0 + (size_t)j * 16,      w0[0]);
                cohstore(h0 + (size_t)j * 16 + 4,  w0[1]);
                cohstore(h0 + (size_t)j * 16 + 8,  w1[0]);
                cohstore(h0 + (size_t)j * 16 + 12, w1[1]);
                cohstore(l0 + (size_t)j * 16,      w2[0]);
                cohstore(l0 + (size_t)j * 16 + 4,  w2[1]);
                cohstore(l0 + (size_t)j * 16 + 8,  w3[0]);
                cohstore(l0 + (size_t)j * 16 + 12, w3[1]);
            }
        }
    }
    __syncthreads();   // drains all waves' vmcnt before barrier (m97)
    if (td == 0) {
        __hip_atomic_store(&flags[wb], 1u, __ATOMIC_RELAXED, __HIP_MEMORY_SCOPE_AGENT);
    }

    // ================= layers 1..17 (MFMA) =================
    for (int li = 1; li < 18; ++li) {
        const int d = 1 << (li < 9 ? li : li - 9);
        const unsigned short* hin_hi = pbase + (size_t)((li - 1) & 1) * (2 * PLANE);
        const unsigned short* hin_lo = hin_hi + PLANE;
        unsigned short* hout_hi = pbase + (size_t)(li & 1) * (2 * PLANE);
        unsigned short* hout_lo = hout_hi + PLANE;

        // stage per-layer smalls into LDS
        if (li < 17) rwl[td] = rwp[li * 256 + td];
        if (td < 16)      sml[td] = mixer_w[li * 16 + td];
        else if (td < 32) sml[td] = (li < 17) ? res_b[li * 16 + td - 16] : 0.f;
        else if (td < 64) sml[td] = fgbias[li * 32 + td - 32];

        // waits at level li-1: fwd wb-1,wb-2 (taps ready), bwd wb+1,wb+2
        // (their reads of the buffer set we overwrite are done)
        if (td == 0 && wb >= 1) spin_on(&flags[(li - 1) * NBLK + wb - 1]);
        if (td == 1 && wb >= 2) spin_on(&flags[(li - 1) * NBLK + wb - 2]);
        if (td == 2 && wb + 1 < NBLK) spin_on(&flags[(li - 1) * NBLK + wb + 1]);
        if (td == 3 && wb + 2 < NBLK) spin_on(&flags[(li - 1) * NBLK + wb + 2]);
        __syncthreads();

        const short8* bfp = (const short8*)(bfrag + li * 3072);
        short8 zero8;
        #pragma unroll
        for (int e = 0; e < 8; ++e) zero8[e] = 0;

        #pragma unroll
        for (int tile = 0; tile < 2; ++tile) {
            const int j = base + tile * 128 + wid * 32 + r0;
            const int t = j & (TL - 1);

            f32x16 acc;
            {
                float4 b0 = *(float4*)&sml[32 + 4 * kh];
                float4 b1 = *(float4*)&sml[40 + 4 * kh];
                float4 b2 = *(float4*)&sml[48 + 4 * kh];
                float4 b3 = *(float4*)&sml[56 + 4 * kh];
                acc[0]=b0.x; acc[1]=b0.y; acc[2]=b0.z; acc[3]=b0.w;
                acc[4]=b1.x; acc[5]=b1.y; acc[6]=b1.z; acc[7]=b1.w;
                acc[8]=b2.x; acc[9]=b2.y; acc[10]=b2.z; acc[11]=b2.w;
                acc[12]=b3.x; acc[13]=b3.y; acc[14]=b3.z; acc[15]=b3.w;
            }

            // serial taps via coherent 8B loads (one tap pair live at a time)
            short8 ah, al;
            #pragma unroll 1
            for (int k = 0; k < 3; ++k) {
                const int off = (k - 2) * d;
                const bool ok = (t + off) >= 0;
                const size_t bofs = (size_t)(ok ? (j + off) : j) * 16 + kh * 8;
                u64 hh[2], ll[2];
                hh[0] = cohload(hin_hi + bofs);
                hh[1] = cohload(hin_hi + bofs + 4);
                ll[0] = cohload(hin_lo + bofs);
                ll[1] = cohload(hin_lo + bofs + 4);
                __builtin_memcpy(&ah, hh, 16);
                __builtin_memcpy(&al, ll, 16);
                if (!ok) { ah = zero8; al = zero8; }
                short8 bh = bfp[(k * 2 + 0) * 64 + lane];
                short8 bl = bfp[(k * 2 + 1) * 64 + lane];
                acc = __builtin_amdgcn_mfma_f32_32x32x16_bf16(bh, ah, acc, 0, 0, 0);
                acc = __builtin_amdgcn_mfma_f32_32x32x16_bf16(bl, ah, acc, 0, 0, 0);
                acc = __builtin_amdgcn_mfma_f32_32x32x16_bf16(bh, al, acc, 0, 0, 0);
            }
            // ah/al now hold tap k=2 (= h at t) for the residual.

            float z8[8];
            #pragma unroll
            for (int r = 0; r < 8; ++r)
                z8[r] = softsign_f(acc[r]) * softsign_f(acc[r + 8]);

            float4 m0 = *(float4*)&sml[4 * kh];
            float4 m1 = *(float4*)&sml[8 + 4 * kh];
            float part = m0.x*z8[0] + m0.y*z8[1] + m0.z*z8[2] + m0.w*z8[3]
                       + m1.x*z8[4] + m1.y*z8[5] + m1.z*z8[6] + m1.w*z8[7];
            float tot = part + __shfl_xor(part, 32);

            if (li == 17) {
                if (kh == 0) out[j] = skipreg[tile] + tot;
            } else {
                if (kh == 0) skipreg[tile] += tot;

                float zo8[8];
                #pragma unroll
                for (int r = 0; r < 8; ++r) zo8[r] = __shfl_xor(z8[r], 32);

                unsigned int uh[4], ul[4];
                __builtin_memcpy(uh, &ah, 16);
                __builtin_memcpy(ul, &al, 16);
                unsigned int sh0 = kh ? uh[0] : uh[2], sh1 = kh ? uh[1] : uh[3];
                unsigned int sl0 = kh ? ul[0] : ul[2], sl1 = kh ? ul[1] : ul[3];
                unsigned int rh0 = (unsigned int)__shfl_xor((int)sh0, 32);
                unsigned int rh1 = (unsigned int)__shfl_xor((int)sh1, 32);
                unsigned int rl0 = (unsigned int)__shfl_xor((int)sl0, 32);
                unsigned int rl1 = (unsigned int)__shfl_xor((int)sl1, 32);
                unsigned int qh0 = kh ? uh[2] : uh[0], qh1 = kh ? uh[3] : uh[1];
                unsigned int ql0 = kh ? ul[2] : ul[0], ql1 = kh ? ul[3] : ul[1];
                unsigned int g1h0 = kh ? rh0 : qh0, g1h1 = kh ? rh1 : qh1;
                unsigned int g2h0 = kh ? qh0 : rh0, g2h1 = kh ? qh1 : rh1;
                unsigned int g1l0 = kh ? rl0 : ql0, g1l1 = kh ? rl1 : ql1;
                unsigned int g2l0 = kh ? ql0 : rl0, g2l1 = kh ? ql1 : rl1;

                float4 rb0 = *(float4*)&sml[16 + 4 * kh];
                float4 rb1 = *(float4*)&sml[24 + 4 * kh];
                float hn[8];
                hn[0] = bf2f(g1h0) + bf2f(g1l0) + rb0.x;
                hn[1] = bf2f(g1h0 >> 16) + bf2f(g1l0 >> 16) + rb0.y;
                hn[2] = bf2f(g1h1) + bf2f(g1l1) + rb0.z;
                hn[3] = bf2f(g1h1 >> 16) + bf2f(g1l1 >> 16) + rb0.w;
                hn[4] = bf2f(g2h0) + bf2f(g2l0) + rb1.x;
                hn[5] = bf2f(g2h0 >> 16) + bf2f(g2l0 >> 16) + rb1.y;
                hn[6] = bf2f(g2h1) + bf2f(g2l1) + rb1.z;
                hn[7] = bf2f(g2h1 >> 16) + bf2f(g2l1 >> 16) + rb1.w;

                #pragma unroll
                for (int i = 0; i < 16; ++i) {
                    const int idx = (i & 3) + 4 * (i >> 3);
                    const int ob  = (i >> 2) & 1;
                    const float zi = (ob == kh) ? z8[idx] : zo8[idx];
                    float4 wA = *(float4*)&rwl[i * 16 + 4 * kh];
                    float4 wB = *(float4*)&rwl[i * 16 + 8 + 4 * kh];
                    hn[0] += wA.x * zi; hn[1] += wA.y * zi;
                    hn[2] += wA.z * zi; hn[3] += wA.w * zi;
                    hn[4] += wB.x * zi; hn[5] += wB.y * zi;
                    hn[6] += wB.z * zi; hn[7] += wB.w * zi;
                }

                ushort4v p1h, p2h, p1l, p2l;
                #pragma unroll
                for (int m = 0; m < 4; ++m) {
                    unsigned short u1 = f2bf(hn[m]);
                    p1h[m] = u1; p1l[m] = f2bf(hn[m] - bf2f(u1));
                    unsigned short u2 = f2bf(hn[4 + m]);
                    p2h[m] = u2; p2l[m] = f2bf(hn[4 + m] - bf2f(u2));
                }
                u64 s0, s1, s2, s3;
                __builtin_memcpy(&s0, &p1h, 8);
                __builtin_memcpy(&s1, &p2h, 8);
                __builtin_memcpy(&s2, &p1l, 8);
                __builtin_memcpy(&s3, &p2l, 8);
                cohstore(hout_hi + (size_t)j * 16 + 4 * kh,     s0);
                cohstore(hout_hi + (size_t)j * 16 + 8 + 4 * kh, s1);
                cohstore(hout_lo + (size_t)j * 16 + 4 * kh,     s2);
                cohstore(hout_lo + (size_t)j * 16 + 8 + 4 * kh, s3);
            }
        }

        if (li < 17) {
            __syncthreads();   // drains all waves' stores (m97) before flag
            if (td == 0) {
                __hip_atomic_store(&flags[li * NBLK + wb], 1u,
                                   __ATOMIC_RELAXED, __HIP_MEMORY_SCOPE_AGENT);
            }
        }
    }
}

extern "C" void kernel_launch(void* const* d_in, const int* in_sizes, int n_in,
                              void* d_out, int out_size, void* d_ws, size_t ws_size,
                              hipStream_t stream) {
    const float* x       = (const float*)d_in[0];
    const float* start_w = (const float*)d_in[1];
    const float* conv_w  = (const float*)d_in[2];
    const float* conv_b  = (const float*)d_in[3];
    const float* gate_w  = (const float*)d_in[4];
    const float* gate_b  = (const float*)d_in[5];
    const float* res_w   = (const float*)d_in[6];
    const float* res_b   = (const float*)d_in[7];
    const float* mixer_w = (const float*)d_in[8];
    float* out = (float*)d_out;

    float* ws = (float*)d_ws;
    unsigned short* bfrag = (unsigned short*)ws;            // 55296 ushorts
    float* fgbias = ws + 27648;                             // 576
    float* rwp    = fgbias + 576;                           // 4352
    float* e0f    = rwp + 4352;                             // 48
    float* e0g    = e0f + 48;                               // 48
    unsigned short* pbase = (unsigned short*)(e0g + 48);    // 2 plane-pairs
    unsigned int* flags = (unsigned int*)(pbase + 4 * PLANE); // 17*1024
    (void)ws_size; (void)in_sizes; (void)n_in; (void)out_size;

    hipMemsetAsync(flags, 0, 17 * NBLK * sizeof(unsigned int), stream);

    pack_kernel<<<236, 256, 0, stream>>>(start_w, conv_w, gate_w, res_w,
                                         conv_b, gate_b,
                                         bfrag, fgbias, rwp, e0f, e0g);

    wavenet_fused<<<NBLK, 256, 0, stream>>>(
        x, start_w, conv_b, gate_b, res_b, mixer_w,
        bfrag, fgbias, rwp, e0f, e0g, pbase, out, flags);
}

// Round 12
// 308.643 us; speedup vs baseline: 5.2981x; 1.2005x over previous
//
#include <hip/hip_runtime.h>
#include <hip/hip_bf16.h>
#include <math.h>

// WaveNet on MI355X — round 12: keep h in XCD-local L2.
// R11 forensics: agent-scope atomics bypass L2 both ways -> 750MB through
// the L3 coherence point at 2.5TB/s = the whole 302us. But with the XCD
// swizzle, 1008/1024 blocks' deps are SAME-XCD. So:
//  - h stores: plain (write-back, stay in local L2; ~0 HBM WRITE)
//  - h tap loads: asm global_load_dwordx4 sc0 (bypass stale L1, hit L2)
//  - cross-XCD (2 boundary blocks/chunk): tiny coherent halo buffer via
//    R11's proven 8B agent atomics; existing flag waits cover RAW and WAR.

typedef __attribute__((ext_vector_type(8))) short short8;
typedef __attribute__((ext_vector_type(16))) float f32x16;
typedef unsigned long long u64;

constexpr int TL = 65536;
constexpr int NTOT = 262144;
constexpr int NBLK = 1024;
constexpr size_t PLANE = 4194304;   // ushorts per plane (NTOT*16)

__device__ __forceinline__ unsigned short f2bf(float v) {
    __hip_bfloat16 b = __float2bfloat16(v);
    unsigned short u; __builtin_memcpy(&u, &b, 2); return u;
}
__device__ __forceinline__ float bf2f(unsigned int u) {
    unsigned int x = (u & 0xffffu) << 16;
    float f; __builtin_memcpy(&f, &x, 4); return f;
}
__device__ __forceinline__ float softsign_f(float v) {
    return v * __builtin_amdgcn_rcpf(1.0f + fabsf(v));
}
__device__ __forceinline__ void spin_on(const unsigned int* f) {
    while (__hip_atomic_load((unsigned int*)f, __ATOMIC_RELAXED,
                             __HIP_MEMORY_SCOPE_AGENT) == 0u) {
        __builtin_amdgcn_s_sleep(8);
    }
}
__device__ __forceinline__ u64 cohload(const unsigned short* p) {
    return __hip_atomic_load((u64*)p, __ATOMIC_RELAXED, __HIP_MEMORY_SCOPE_AGENT);
}
__device__ __forceinline__ void cohstore(unsigned short* p, u64 v) {
    __hip_atomic_store((u64*)p, v, __ATOMIC_RELAXED, __HIP_MEMORY_SCOPE_AGENT);
}
// L1-bypass (sc0) 16B pair load + waitcnt in one asm block (rule #18 safe:
// consumers depend on the asm outputs).
__device__ __forceinline__ void l2load2(const unsigned short* ph,
                                        const unsigned short* pl,
                                        short8& vh, short8& vl) {
    asm volatile("global_load_dwordx4 %0, %2, off sc0\n\t"
                 "global_load_dwordx4 %1, %3, off sc0\n\t"
                 "s_waitcnt vmcnt(0)"
                 : "=&v"(vh), "=&v"(vl)
                 : "v"(ph), "v"(pl)
                 : "memory");
}

// ---------------- weight packing (same layout as R8-R11) ----------------
__global__ __launch_bounds__(256) void pack_kernel(
    const float* __restrict__ start_w,
    const float* __restrict__ conv_w,
    const float* __restrict__ gate_w,
    const float* __restrict__ res_w,
    const float* __restrict__ conv_b,
    const float* __restrict__ gate_b,
    unsigned short* __restrict__ bfrag,
    float* __restrict__ fgbias,
    float* __restrict__ rwp,
    float* __restrict__ e0f, float* __restrict__ e0g)
{
    int idx = blockIdx.x * 256 + threadIdx.x;
    if (idx < 55296) {                       // 18*3*2*64*8
        int li = idx / 3072, r = idx % 3072;
        int tap = r / 1024, r2 = r % 1024;
        int p = r2 / 512, r3 = r2 % 512;
        int lane = r3 / 8, j = r3 % 8;
        int n = lane & 31, kh = lane >> 5;
        int i_ch = kh * 8 + j, o = n & 15;
        const float* src = (n < 16) ? conv_w : gate_w;
        float w = src[((li * 16 + o) * 16 + i_ch) * 3 + tap];
        unsigned short hi = f2bf(w);
        bfrag[idx] = (p == 0) ? hi : f2bf(w - bf2f(hi));
    } else if (idx < 55296 + 576) {
        int u = idx - 55296; int li = u / 32, n = u % 32;
        fgbias[u] = (n < 16) ? conv_b[li * 16 + n] : gate_b[li * 16 + n - 16];
    } else if (idx < 55296 + 576 + 4352) {
        int u = idx - 55872; int li = u / 256, r = u % 256, i = r / 16, o = r % 16;
        rwp[u] = res_w[(li * 16 + o) * 16 + i];
    } else if (idx < 60320) {
        int u = idx - 60224; int which = u / 48, r = u % 48, k = r / 16, o = r % 16;
        const float* src = which ? gate_w : conv_w;
        float s = 0.f;
        #pragma unroll
        for (int i = 0; i < 16; ++i) s += src[(o * 16 + i) * 3 + k] * start_w[i];
        (which ? e0g : e0f)[k * 16 + o] = s;
    }
}

// ---------------- persistent fused kernel ----------------
__global__ __launch_bounds__(256, 4) void wavenet_fused(
    const float* __restrict__ x,
    const float* __restrict__ start_w,
    const float* __restrict__ conv_b,
    const float* __restrict__ gate_b,
    const float* __restrict__ res_b,
    const float* __restrict__ mixer_w,
    const unsigned short* __restrict__ bfrag,
    const float* __restrict__ fgbias,
    const float* __restrict__ rwp,
    const float* __restrict__ e0f,
    const float* __restrict__ e0g,
    unsigned short* __restrict__ pbase,   // 2 plane-pairs (hi,lo)
    unsigned short* __restrict__ halo,    // [2 sets][8 chunks][512 rows][32]
    float* __restrict__ out,
    unsigned int* __restrict__ flags)     // [17][NBLK]
{
    __shared__ float rwl[256];
    __shared__ float sml[64];   // [0:16) mx  [16:32) rb  [32:64) fgbias

    const int td   = threadIdx.x;
    const int wid  = td >> 6;
    const int lane = td & 63;
    const int r0   = lane & 31;
    const int kh   = lane >> 5;
    const int wb   = ((int)blockIdx.x & 7) * (NBLK >> 3) + ((int)blockIdx.x >> 3);
    const int base = wb * 256;
    const bool is_halo_prod = (wb & 127) >= 126;

    float skipreg[2];

    // ================= layer 0 (VALU, tiny) =================
    {
        unsigned short* h0 = pbase;
        unsigned short* l0 = pbase + PLANE;
        #pragma unroll
        for (int tile = 0; tile < 2; ++tile) {
            const int j = base + tile * 128 + wid * 32 + r0;
            const int t = j & (TL - 1);
            const float x2 = x[j];
            const float x1 = (t >= 1) ? x[j - 1] : 0.f;
            const float x0 = (t >= 2) ? x[j - 2] : 0.f;
            const float xs[3] = {x0, x1, x2};
            float fv[16], qv[16];
            #pragma unroll
            for (int o = 0; o < 16; ++o) { fv[o] = conv_b[o]; qv[o] = gate_b[o]; }
            #pragma unroll
            for (int k = 0; k < 3; ++k) {
                #pragma unroll
                for (int o = 0; o < 16; ++o) {
                    fv[o] += e0f[k * 16 + o] * xs[k];
                    qv[o] += e0g[k * 16 + o] * xs[k];
                }
            }
            float z[16];
            #pragma unroll
            for (int o = 0; o < 16; ++o) z[o] = softsign_f(fv[o]) * softsign_f(qv[o]);
            float s = 0.f;
            #pragma unroll
            for (int o = 0; o < 16; ++o) s += mixer_w[o] * z[o];
            skipreg[tile] = s;
            float hn[16];
            #pragma unroll
            for (int o = 0; o < 16; ++o) hn[o] = start_w[o] * x2 + res_b[o];
            #pragma unroll
            for (int i = 0; i < 16; ++i) {
                #pragma unroll
                for (int o = 0; o < 16; ++o) hn[o] += rwp[i * 16 + o] * z[i];
            }
            if (kh == 0) {
                u64 wh[4], wl[4];
                #pragma unroll
                for (int p4 = 0; p4 < 4; ++p4) {
                    unsigned short hbuf[4], lbuf[4];
                    #pragma unroll
                    for (int m = 0; m < 4; ++m) {
                        unsigned short u = f2bf(hn[p4 * 4 + m]);
                        hbuf[m] = u; lbuf[m] = f2bf(hn[p4 * 4 + m] - bf2f(u));
                    }
                    __builtin_memcpy(&wh[p4], hbuf, 8);
                    __builtin_memcpy(&wl[p4], lbuf, 8);
                }
                u64* dh = (u64*)(h0 + (size_t)j * 16);
                u64* dl = (u64*)(l0 + (size_t)j * 16);
                dh[0] = wh[0]; dh[1] = wh[1]; dh[2] = wh[2]; dh[3] = wh[3];
                dl[0] = wl[0]; dl[1] = wl[1]; dl[2] = wl[2]; dl[3] = wl[3];
                if (is_halo_prod) {
                    unsigned short* hb = halo
                        + (size_t)(wb >> 7) * 16384
                        + (size_t)((j & 32767) - 32256) * 32;
                    cohstore(hb + 0,  wh[0]); cohstore(hb + 4,  wh[1]);
                    cohstore(hb + 8,  wh[2]); cohstore(hb + 12, wh[3]);
                    cohstore(hb + 16, wl[0]); cohstore(hb + 20, wl[1]);
                    cohstore(hb + 24, wl[2]); cohstore(hb + 28, wl[3]);
                }
            }
        }
    }
    __syncthreads();   // drains vmcnt pre-barrier => stores in L2/L3 first
    if (td == 0) {
        __hip_atomic_store(&flags[wb], 1u, __ATOMIC_RELAXED, __HIP_MEMORY_SCOPE_AGENT);
    }

    // ================= layers 1..17 (MFMA) =================
    for (int li = 1; li < 18; ++li) {
        const int d = 1 << (li < 9 ? li : li - 9);
        const unsigned short* hin_hi = pbase + (size_t)((li - 1) & 1) * (2 * PLANE);
        const unsigned short* hin_lo = hin_hi + PLANE;
        unsigned short* hout_hi = pbase + (size_t)(li & 1) * (2 * PLANE);
        unsigned short* hout_lo = hout_hi + PLANE;
        const unsigned short* halo_in = halo + (size_t)((li - 1) & 1) * 131072;
        unsigned short* halo_out = halo + (size_t)(li & 1) * 131072;

        if (li < 17) rwl[td] = rwp[li * 256 + td];
        if (td < 16)      sml[td] = mixer_w[li * 16 + td];
        else if (td < 32) sml[td] = (li < 17) ? res_b[li * 16 + td - 16] : 0.f;
        else if (td < 64) sml[td] = fgbias[li * 32 + td - 32];

        // fwd: wb-1,wb-2 (taps + halo ready); bwd: wb+1,wb+2 (reads of the
        // buffer set + halo set we overwrite are done)
        if (td == 0 && wb >= 1) spin_on(&flags[(li - 1) * NBLK + wb - 1]);
        if (td == 1 && wb >= 2) spin_on(&flags[(li - 1) * NBLK + wb - 2]);
        if (td == 2 && wb + 1 < NBLK) spin_on(&flags[(li - 1) * NBLK + wb + 1]);
        if (td == 3 && wb + 2 < NBLK) spin_on(&flags[(li - 1) * NBLK + wb + 2]);
        __syncthreads();

        const short8* bfp = (const short8*)(bfrag + li * 3072);
        short8 zero8;
        #pragma unroll
        for (int e = 0; e < 8; ++e) zero8[e] = 0;

        #pragma unroll
        for (int tile = 0; tile < 2; ++tile) {
            const int j = base + tile * 128 + wid * 32 + r0;
            const int t = j & (TL - 1);

            f32x16 acc;
            {
                float4 b0 = *(float4*)&sml[32 + 4 * kh];
                float4 b1 = *(float4*)&sml[40 + 4 * kh];
                float4 b2 = *(float4*)&sml[48 + 4 * kh];
                float4 b3 = *(float4*)&sml[56 + 4 * kh];
                acc[0]=b0.x; acc[1]=b0.y; acc[2]=b0.z; acc[3]=b0.w;
                acc[4]=b1.x; acc[5]=b1.y; acc[6]=b1.z; acc[7]=b1.w;
                acc[8]=b2.x; acc[9]=b2.y; acc[10]=b2.z; acc[11]=b2.w;
                acc[12]=b3.x; acc[13]=b3.y; acc[14]=b3.z; acc[15]=b3.w;
            }

            short8 ah, al;
            #pragma unroll 1
            for (int k = 0; k < 3; ++k) {
                const int off = (k - 2) * d;
                const bool ok = (t + off) >= 0;
                const int rrow = ok ? (j + off) : j;
                short8 ah_, al_;
                if (ok && ((rrow >> 15) != (j >> 15))) {
                    // cross-XCD: read the coherent halo mirror
                    const unsigned short* hb = halo_in
                        + (size_t)(rrow >> 15) * 16384
                        + (size_t)((rrow & 32767) - 32256) * 32;
                    u64 hh[2], ll[2];
                    hh[0] = cohload(hb + 8 * kh);
                    hh[1] = cohload(hb + 8 * kh + 4);
                    ll[0] = cohload(hb + 16 + 8 * kh);
                    ll[1] = cohload(hb + 16 + 8 * kh + 4);
                    __builtin_memcpy(&ah_, hh, 16);
                    __builtin_memcpy(&al_, ll, 16);
                } else {
                    const size_t bofs = (size_t)rrow * 16 + kh * 8;
                    l2load2(hin_hi + bofs, hin_lo + bofs, ah_, al_);
                    if (!ok) { ah_ = zero8; al_ = zero8; }
                }
                ah = ah_; al = al_;
                short8 bh = bfp[(k * 2 + 0) * 64 + lane];
                short8 bl = bfp[(k * 2 + 1) * 64 + lane];
                acc = __builtin_amdgcn_mfma_f32_32x32x16_bf16(bh, ah, acc, 0, 0, 0);
                acc = __builtin_amdgcn_mfma_f32_32x32x16_bf16(bl, ah, acc, 0, 0, 0);
                acc = __builtin_amdgcn_mfma_f32_32x32x16_bf16(bh, al, acc, 0, 0, 0);
            }
            // ah/al hold tap k=2 (= h at t) for the residual.

            float z8[8];
            #pragma unroll
            for (int r = 0; r < 8; ++r)
                z8[r] = softsign_f(acc[r]) * softsign_f(acc[r + 8]);

            float4 m0 = *(float4*)&sml[4 * kh];
            float4 m1 = *(float4*)&sml[8 + 4 * kh];
            float part = m0.x*z8[0] + m0.y*z8[1] + m0.z*z8[2] + m0.w*z8[3]
                       + m1.x*z8[4] + m1.y*z8[5] + m1.z*z8[6] + m1.w*z8[7];
            float tot = part + __shfl_xor(part, 32);

            if (li == 17) {
                if (kh == 0) out[j] = skipreg[tile] + tot;
            } else {
                if (kh == 0) skipreg[tile] += tot;

                float zo8[8];
                #pragma unroll
                for (int r = 0; r < 8; ++r) zo8[r] = __shfl_xor(z8[r], 32);

                unsigned int uh[4], ul[4];
                __builtin_memcpy(uh, &ah, 16);
                __builtin_memcpy(ul, &al, 16);
                unsigned int sh0 = kh ? uh[0] : uh[2], sh1 = kh ? uh[1] : uh[3];
                unsigned int sl0 = kh ? ul[0] : ul[2], sl1 = kh ? ul[1] : ul[3];
                unsigned int rh0 = (unsigned int)__shfl_xor((int)sh0, 32);
                unsigned int rh1 = (unsigned int)__shfl_xor((int)sh1, 32);
                unsigned int rl0 = (unsigned int)__shfl_xor((int)sl0, 32);
                unsigned int rl1 = (unsigned int)__shfl_xor((int)sl1, 32);
                unsigned int qh0 = kh ? uh[2] : uh[0], qh1 = kh ? uh[3] : uh[1];
                unsigned int ql0 = kh ? ul[2] : ul[0], ql1 = kh ? ul[3] : ul[1];
                unsigned int g1h0 = kh ? rh0 : qh0, g1h1 = kh ? rh1 : qh1;
                unsigned int g2h0 = kh ? qh0 : rh0, g2h1 = kh ? qh1 : rh1;
                unsigned int g1l0 = kh ? rl0 : ql0, g1l1 = kh ? rl1 : ql1;
                unsigned int g2l0 = kh ? ql0 : rl0, g2l1 = kh ? ql1 : rl1;

                float4 rb0 = *(float4*)&sml[16 + 4 * kh];
                float4 rb1 = *(float4*)&sml[24 + 4 * kh];
                float hn[8];
                hn[0] = bf2f(g1h0) + bf2f(g1l0) + rb0.x;
                hn[1] = bf2f(g1h0 >> 16) + bf2f(g1l0 >> 16) + rb0.y;
                hn[2] = bf2f(g1h1) + bf2f(g1l1) + rb0.z;
                hn[3] = bf2f(g1h1 >> 16) + bf2f(g1l1 >> 16) + rb0.w;
                hn[4] = bf2f(g2h0) + bf2f(g2l0) + rb1.x;
                hn[5] = bf2f(g2h0 >> 16) + bf2f(g2l0 >> 16) + rb1.y;
                hn[6] = bf2f(g2h1) + bf2f(g2l1) + rb1.z;
                hn[7] = bf2f(g2h1 >> 16) + bf2f(g2l1 >> 16) + rb1.w;

                #pragma unroll
                for (int i = 0; i < 16; ++i) {
                    const int idx = (i & 3) + 4 * (i >> 3);
                    const int ob  = (i >> 2) & 1;
                    const float zi = (ob == kh) ? z8[idx] : zo8[idx];
                    float4 wA = *(float4*)&rwl[i * 16 + 4 * kh];
                    float4 wB = *(float4*)&rwl[i * 16 + 8 + 4 * kh];
                    hn[0] += wA.x * zi; hn[1] += wA.y * zi;
                    hn[2] += wA.z * zi; hn[3] += wA.w * zi;
                    hn[4] += wB.x * zi; hn[5] += wB.y * zi;
                    hn[6] += wB.z * zi; hn[7] += wB.w * zi;
                }

                u64 s0, s1, s2, s3;
                {
                    unsigned short b0[4], b1[4], b2[4], b3[4];
                    #pragma unroll
                    for (int m = 0; m < 4; ++m) {
                        unsigned short u1 = f2bf(hn[m]);
                        b0[m] = u1; b2[m] = f2bf(hn[m] - bf2f(u1));
                        unsigned short u2 = f2bf(hn[4 + m]);
                        b1[m] = u2; b3[m] = f2bf(hn[4 + m] - bf2f(u2));
                    }
                    __builtin_memcpy(&s0, b0, 8);
                    __builtin_memcpy(&s1, b1, 8);
                    __builtin_memcpy(&s2, b2, 8);
                    __builtin_memcpy(&s3, b3, 8);
                }
                // plain write-back stores: stay in local XCD L2
                *(u64*)(hout_hi + (size_t)j * 16 + 4 * kh)     = s0;
                *(u64*)(hout_hi + (size_t)j * 16 + 8 + 4 * kh) = s1;
                *(u64*)(hout_lo + (size_t)j * 16 + 4 * kh)     = s2;
                *(u64*)(hout_lo + (size_t)j * 16 + 8 + 4 * kh) = s3;
                if (is_halo_prod) {
                    unsigned short* hb = halo_out
                        + (size_t)(wb >> 7) * 16384
                        + (size_t)((j & 32767) - 32256) * 32;
                    cohstore(hb + 4 * kh,          s0);
                    cohstore(hb + 8 + 4 * kh,      s1);
                    cohstore(hb + 16 + 4 * kh,     s2);
                    cohstore(hb + 16 + 8 + 4 * kh, s3);
                }
            }
        }

        if (li < 17) {
            __syncthreads();   // drains stores (L2 + halo) before flag
            if (td == 0) {
                __hip_atomic_store(&flags[li * NBLK + wb], 1u,
                                   __ATOMIC_RELAXED, __HIP_MEMORY_SCOPE_AGENT);
            }
        }
    }
}

extern "C" void kernel_launch(void* const* d_in, const int* in_sizes, int n_in,
                              void* d_out, int out_size, void* d_ws, size_t ws_size,
                              hipStream_t stream) {
    const float* x       = (const float*)d_in[0];
    const float* start_w = (const float*)d_in[1];
    const float* conv_w  = (const float*)d_in[2];
    const float* conv_b  = (const float*)d_in[3];
    const float* gate_w  = (const float*)d_in[4];
    const float* gate_b  = (const float*)d_in[5];
    const float* res_w   = (const float*)d_in[6];
    const float* res_b   = (const float*)d_in[7];
    const float* mixer_w = (const float*)d_in[8];
    float* out = (float*)d_out;

    float* ws = (float*)d_ws;
    unsigned short* bfrag = (unsigned short*)ws;            // 55296 ushorts
    float* fgbias = ws + 27648;                             // 576
    float* rwp    = fgbias + 576;                           // 4352
    float* e0f    = rwp + 4352;                             // 48
    float* e0g    = e0f + 48;                               // 48
    unsigned short* pbase = (unsigned short*)(e0g + 48);    // 2 plane-pairs
    unsigned short* halo  = pbase + 4 * PLANE;              // 2x8x512x32 ushorts
    unsigned int* flags = (unsigned int*)(halo + 262144);   // 17*1024
    (void)ws_size; (void)in_sizes; (void)n_in; (void)out_size;

    hipMemsetAsync(flags, 0, 17 * NBLK * sizeof(unsigned int), stream);

    pack_kernel<<<236, 256, 0, stream>>>(start_w, conv_w, gate_w, res_w,
                                         conv_b, gate_b,
                                         bfrag, fgbias, rwp, e0f, e0g);

    wavenet_fused<<<NBLK, 256, 0, stream>>>(
        x, start_w, conv_b, gate_b, res_b, mixer_w,
        bfrag, fgbias, rwp, e0f, e0g, pbase, halo, out, flags);
}

// Round 13
// 300.493 us; speedup vs baseline: 5.4418x; 1.0271x over previous
//
#include <hip/hip_runtime.h>
#include <hip/hip_bf16.h>
#include <math.h>

// WaveNet on MI355X — round 13: one latency exposure per tile.
// R12 forensics: FETCH 141->33MB (L2-local h works) but 14.5us/layer vs
// ~3us model. Dominant residual: 3 serialized {2-load + vmcnt(0)} asm blocks
// per tile = 3x full L2/HBM latency, with only ~3 waves/SIMD TLP to hide.
// Fix: single asm block per tile issuing all 6 sc0 tap loads + ONE wait
// (fast path, valid for 1008/1024 blocks); boundary blocks keep R12's
// per-tap halo path. b-frags via plain C++ loads (compiler schedules).
// Spin sleep 8->2. WRITE 288MB = L2 eviction churn (4MB set = L2 size),
// accepted this round.

typedef __attribute__((ext_vector_type(8))) short short8;
typedef __attribute__((ext_vector_type(16))) float f32x16;
typedef unsigned long long u64;

constexpr int TL = 65536;
constexpr int NTOT = 262144;
constexpr int NBLK = 1024;
constexpr size_t PLANE = 4194304;   // ushorts per plane (NTOT*16)

__device__ __forceinline__ unsigned short f2bf(float v) {
    __hip_bfloat16 b = __float2bfloat16(v);
    unsigned short u; __builtin_memcpy(&u, &b, 2); return u;
}
__device__ __forceinline__ float bf2f(unsigned int u) {
    unsigned int x = (u & 0xffffu) << 16;
    float f; __builtin_memcpy(&f, &x, 4); return f;
}
__device__ __forceinline__ float softsign_f(float v) {
    return v * __builtin_amdgcn_rcpf(1.0f + fabsf(v));
}
__device__ __forceinline__ void spin_on(const unsigned int* f) {
    while (__hip_atomic_load((unsigned int*)f, __ATOMIC_RELAXED,
                             __HIP_MEMORY_SCOPE_AGENT) == 0u) {
        __builtin_amdgcn_s_sleep(2);
    }
}
__device__ __forceinline__ u64 cohload(const unsigned short* p) {
    return __hip_atomic_load((u64*)p, __ATOMIC_RELAXED, __HIP_MEMORY_SCOPE_AGENT);
}
__device__ __forceinline__ void cohstore(unsigned short* p, u64 v) {
    __hip_atomic_store((u64*)p, v, __ATOMIC_RELAXED, __HIP_MEMORY_SCOPE_AGENT);
}
// per-tap L1-bypass pair load (slow/boundary path only)
__device__ __forceinline__ void l2load2(const unsigned short* ph,
                                        const unsigned short* pl,
                                        short8& vh, short8& vl) {
    asm volatile("global_load_dwordx4 %0, %2, off sc0\n\t"
                 "global_load_dwordx4 %1, %3, off sc0\n\t"
                 "s_waitcnt vmcnt(0)"
                 : "=&v"(vh), "=&v"(vl)
                 : "v"(ph), "v"(pl)
                 : "memory");
}

// ---------------- weight packing (same layout as R8-R12) ----------------
__global__ __launch_bounds__(256) void pack_kernel(
    const float* __restrict__ start_w,
    const float* __restrict__ conv_w,
    const float* __restrict__ gate_w,
    const float* __restrict__ res_w,
    const float* __restrict__ conv_b,
    const float* __restrict__ gate_b,
    unsigned short* __restrict__ bfrag,
    float* __restrict__ fgbias,
    float* __restrict__ rwp,
    float* __restrict__ e0f, float* __restrict__ e0g)
{
    int idx = blockIdx.x * 256 + threadIdx.x;
    if (idx < 55296) {                       // 18*3*2*64*8
        int li = idx / 3072, r = idx % 3072;
        int tap = r / 1024, r2 = r % 1024;
        int p = r2 / 512, r3 = r2 % 512;
        int lane = r3 / 8, j = r3 % 8;
        int n = lane & 31, kh = lane >> 5;
        int i_ch = kh * 8 + j, o = n & 15;
        const float* src = (n < 16) ? conv_w : gate_w;
        float w = src[((li * 16 + o) * 16 + i_ch) * 3 + tap];
        unsigned short hi = f2bf(w);
        bfrag[idx] = (p == 0) ? hi : f2bf(w - bf2f(hi));
    } else if (idx < 55296 + 576) {
        int u = idx - 55296; int li = u / 32, n = u % 32;
        fgbias[u] = (n < 16) ? conv_b[li * 16 + n] : gate_b[li * 16 + n - 16];
    } else if (idx < 55296 + 576 + 4352) {
        int u = idx - 55872; int li = u / 256, r = u % 256, i = r / 16, o = r % 16;
        rwp[u] = res_w[(li * 16 + o) * 16 + i];
    } else if (idx < 60320) {
        int u = idx - 60224; int which = u / 48, r = u % 48, k = r / 16, o = r % 16;
        const float* src = which ? gate_w : conv_w;
        float s = 0.f;
        #pragma unroll
        for (int i = 0; i < 16; ++i) s += src[(o * 16 + i) * 3 + k] * start_w[i];
        (which ? e0g : e0f)[k * 16 + o] = s;
    }
}

// ---------------- persistent fused kernel ----------------
__global__ __launch_bounds__(256, 4) void wavenet_fused(
    const float* __restrict__ x,
    const float* __restrict__ start_w,
    const float* __restrict__ conv_b,
    const float* __restrict__ gate_b,
    const float* __restrict__ res_b,
    const float* __restrict__ mixer_w,
    const unsigned short* __restrict__ bfrag,
    const float* __restrict__ fgbias,
    const float* __restrict__ rwp,
    const float* __restrict__ e0f,
    const float* __restrict__ e0g,
    unsigned short* __restrict__ pbase,   // 2 plane-pairs (hi,lo)
    unsigned short* __restrict__ halo,    // [2 sets][8 chunks][512 rows][32]
    float* __restrict__ out,
    unsigned int* __restrict__ flags)     // [17][NBLK]
{
    __shared__ float rwl[256];
    __shared__ float sml[64];   // [0:16) mx  [16:32) rb  [32:64) fgbias

    const int td   = threadIdx.x;
    const int wid  = td >> 6;
    const int lane = td & 63;
    const int r0   = lane & 31;
    const int kh   = lane >> 5;
    const int wb   = ((int)blockIdx.x & 7) * (NBLK >> 3) + ((int)blockIdx.x >> 3);
    const int base = wb * 256;
    const bool is_halo_prod = (wb & 127) >= 126;
    // fast: no tap of this block can cross a chunk boundary (chunk 0 never
    // crosses: negative taps are zero-masked)
    const bool fastblk = ((wb & 127) >= 2) || (wb >> 7) == 0;

    float skipreg[2];

    // ================= layer 0 (VALU, tiny) =================
    {
        unsigned short* h0 = pbase;
        unsigned short* l0 = pbase + PLANE;
        #pragma unroll
        for (int tile = 0; tile < 2; ++tile) {
            const int j = base + tile * 128 + wid * 32 + r0;
            const int t = j & (TL - 1);
            const float x2 = x[j];
            const float x1 = (t >= 1) ? x[j - 1] : 0.f;
            const float x0 = (t >= 2) ? x[j - 2] : 0.f;
            const float xs[3] = {x0, x1, x2};
            float fv[16], qv[16];
            #pragma unroll
            for (int o = 0; o < 16; ++o) { fv[o] = conv_b[o]; qv[o] = gate_b[o]; }
            #pragma unroll
            for (int k = 0; k < 3; ++k) {
                #pragma unroll
                for (int o = 0; o < 16; ++o) {
                    fv[o] += e0f[k * 16 + o] * xs[k];
                    qv[o] += e0g[k * 16 + o] * xs[k];
                }
            }
            float z[16];
            #pragma unroll
            for (int o = 0; o < 16; ++o) z[o] = softsign_f(fv[o]) * softsign_f(qv[o]);
            float s = 0.f;
            #pragma unroll
            for (int o = 0; o < 16; ++o) s += mixer_w[o] * z[o];
            skipreg[tile] = s;
            float hn[16];
            #pragma unroll
            for (int o = 0; o < 16; ++o) hn[o] = start_w[o] * x2 + res_b[o];
            #pragma unroll
            for (int i = 0; i < 16; ++i) {
                #pragma unroll
                for (int o = 0; o < 16; ++o) hn[o] += rwp[i * 16 + o] * z[i];
            }
            if (kh == 0) {
                u64 wh[4], wl[4];
                #pragma unroll
                for (int p4 = 0; p4 < 4; ++p4) {
                    unsigned short hbuf[4], lbuf[4];
                    #pragma unroll
                    for (int m = 0; m < 4; ++m) {
                        unsigned short u = f2bf(hn[p4 * 4 + m]);
                        hbuf[m] = u; lbuf[m] = f2bf(hn[p4 * 4 + m] - bf2f(u));
                    }
                    __builtin_memcpy(&wh[p4], hbuf, 8);
                    __builtin_memcpy(&wl[p4], lbuf, 8);
                }
                u64* dh = (u64*)(h0 + (size_t)j * 16);
                u64* dl = (u64*)(l0 + (size_t)j * 16);
                dh[0] = wh[0]; dh[1] = wh[1]; dh[2] = wh[2]; dh[3] = wh[3];
                dl[0] = wl[0]; dl[1] = wl[1]; dl[2] = wl[2]; dl[3] = wl[3];
                if (is_halo_prod) {
                    unsigned short* hb = halo
                        + (size_t)(wb >> 7) * 16384
                        + (size_t)((j & 32767) - 32256) * 32;
                    cohstore(hb + 0,  wh[0]); cohstore(hb + 4,  wh[1]);
                    cohstore(hb + 8,  wh[2]); cohstore(hb + 12, wh[3]);
                    cohstore(hb + 16, wl[0]); cohstore(hb + 20, wl[1]);
                    cohstore(hb + 24, wl[2]); cohstore(hb + 28, wl[3]);
                }
            }
        }
    }
    __syncthreads();   // drains vmcnt pre-barrier => stores in L2/L3 first
    if (td == 0) {
        __hip_atomic_store(&flags[wb], 1u, __ATOMIC_RELAXED, __HIP_MEMORY_SCOPE_AGENT);
    }

    // ================= layers 1..17 (MFMA) =================
    for (int li = 1; li < 18; ++li) {
        const int d = 1 << (li < 9 ? li : li - 9);
        const unsigned short* hin_hi = pbase + (size_t)((li - 1) & 1) * (2 * PLANE);
        const unsigned short* hin_lo = hin_hi + PLANE;
        unsigned short* hout_hi = pbase + (size_t)(li & 1) * (2 * PLANE);
        unsigned short* hout_lo = hout_hi + PLANE;
        const unsigned short* halo_in = halo + (size_t)((li - 1) & 1) * 131072;
        unsigned short* halo_out = halo + (size_t)(li & 1) * 131072;

        if (li < 17) rwl[td] = rwp[li * 256 + td];
        if (td < 16)      sml[td] = mixer_w[li * 16 + td];
        else if (td < 32) sml[td] = (li < 17) ? res_b[li * 16 + td - 16] : 0.f;
        else if (td < 64) sml[td] = fgbias[li * 32 + td - 32];

        if (td == 0 && wb >= 1) spin_on(&flags[(li - 1) * NBLK + wb - 1]);
        if (td == 1 && wb >= 2) spin_on(&flags[(li - 1) * NBLK + wb - 2]);
        if (td == 2 && wb + 1 < NBLK) spin_on(&flags[(li - 1) * NBLK + wb + 1]);
        if (td == 3 && wb + 2 < NBLK) spin_on(&flags[(li - 1) * NBLK + wb + 2]);
        __syncthreads();

        const short8* bfp = (const short8*)(bfrag + li * 3072);
        short8 zero8;
        #pragma unroll
        for (int e = 0; e < 8; ++e) zero8[e] = 0;

        #pragma unroll
        for (int tile = 0; tile < 2; ++tile) {
            const int j = base + tile * 128 + wid * 32 + r0;
            const int t = j & (TL - 1);

            f32x16 acc;
            {
                float4 b0 = *(float4*)&sml[32 + 4 * kh];
                float4 b1 = *(float4*)&sml[40 + 4 * kh];
                float4 b2 = *(float4*)&sml[48 + 4 * kh];
                float4 b3 = *(float4*)&sml[56 + 4 * kh];
                acc[0]=b0.x; acc[1]=b0.y; acc[2]=b0.z; acc[3]=b0.w;
                acc[4]=b1.x; acc[5]=b1.y; acc[6]=b1.z; acc[7]=b1.w;
                acc[8]=b2.x; acc[9]=b2.y; acc[10]=b2.z; acc[11]=b2.w;
                acc[12]=b3.x; acc[13]=b3.y; acc[14]=b3.z; acc[15]=b3.w;
            }

            short8 ah, al;   // tap k=2 (own row), kept for the residual
            if (fastblk) {
                // ---- single asm block: 6 sc0 loads, ONE vmcnt(0) ----
                const bool ok0 = (t - 2 * d) >= 0;
                const bool ok1 = (t - d) >= 0;
                const size_t o0 = (size_t)(ok0 ? (j - 2 * d) : j) * 16 + kh * 8;
                const size_t o1 = (size_t)(ok1 ? (j - d)     : j) * 16 + kh * 8;
                const size_t o2 = (size_t)j * 16 + kh * 8;
                short8 a0h, a0l, a1h, a1l;
                asm volatile(
                    "global_load_dwordx4 %0, %6, off sc0\n\t"
                    "global_load_dwordx4 %1, %7, off sc0\n\t"
                    "global_load_dwordx4 %2, %8, off sc0\n\t"
                    "global_load_dwordx4 %3, %9, off sc0\n\t"
                    "global_load_dwordx4 %4, %10, off sc0\n\t"
                    "global_load_dwordx4 %5, %11, off sc0\n\t"
                    "s_waitcnt vmcnt(0)"
                    : "=&v"(a0h), "=&v"(a0l), "=&v"(a1h),
                      "=&v"(a1l), "=&v"(ah),  "=&v"(al)
                    : "v"(hin_hi + o0), "v"(hin_lo + o0),
                      "v"(hin_hi + o1), "v"(hin_lo + o1),
                      "v"(hin_hi + o2), "v"(hin_lo + o2)
                    : "memory");
                if (!ok0) { a0h = zero8; a0l = zero8; }
                if (!ok1) { a1h = zero8; a1l = zero8; }
                short8 bh0 = bfp[0 * 64 + lane], bl0 = bfp[1 * 64 + lane];
                short8 bh1 = bfp[2 * 64 + lane], bl1 = bfp[3 * 64 + lane];
                short8 bh2 = bfp[4 * 64 + lane], bl2 = bfp[5 * 64 + lane];
                acc = __builtin_amdgcn_mfma_f32_32x32x16_bf16(bh0, a0h, acc, 0, 0, 0);
                acc = __builtin_amdgcn_mfma_f32_32x32x16_bf16(bl0, a0h, acc, 0, 0, 0);
                acc = __builtin_amdgcn_mfma_f32_32x32x16_bf16(bh0, a0l, acc, 0, 0, 0);
                acc = __builtin_amdgcn_mfma_f32_32x32x16_bf16(bh1, a1h, acc, 0, 0, 0);
                acc = __builtin_amdgcn_mfma_f32_32x32x16_bf16(bl1, a1h, acc, 0, 0, 0);
                acc = __builtin_amdgcn_mfma_f32_32x32x16_bf16(bh1, a1l, acc, 0, 0, 0);
                acc = __builtin_amdgcn_mfma_f32_32x32x16_bf16(bh2, ah,  acc, 0, 0, 0);
                acc = __builtin_amdgcn_mfma_f32_32x32x16_bf16(bl2, ah,  acc, 0, 0, 0);
                acc = __builtin_amdgcn_mfma_f32_32x32x16_bf16(bh2, al,  acc, 0, 0, 0);
            } else {
                // ---- boundary blocks: per-tap with halo (R12 path) ----
                #pragma unroll 1
                for (int k = 0; k < 3; ++k) {
                    const int off = (k - 2) * d;
                    const bool ok = (t + off) >= 0;
                    const int rrow = ok ? (j + off) : j;
                    short8 ah_, al_;
                    if (ok && ((rrow >> 15) != (j >> 15))) {
                        const unsigned short* hb = halo_in
                            + (size_t)(rrow >> 15) * 16384
                            + (size_t)((rrow & 32767) - 32256) * 32;
                        u64 hh[2], ll[2];
                        hh[0] = cohload(hb + 8 * kh);
                        hh[1] = cohload(hb + 8 * kh + 4);
                        ll[0] = cohload(hb + 16 + 8 * kh);
                        ll[1] = cohload(hb + 16 + 8 * kh + 4);
                        __builtin_memcpy(&ah_, hh, 16);
                        __builtin_memcpy(&al_, ll, 16);
                    } else {
                        const size_t bofs = (size_t)rrow * 16 + kh * 8;
                        l2load2(hin_hi + bofs, hin_lo + bofs, ah_, al_);
                        if (!ok) { ah_ = zero8; al_ = zero8; }
                    }
                    ah = ah_; al = al_;
                    short8 bh = bfp[(k * 2 + 0) * 64 + lane];
                    short8 bl = bfp[(k * 2 + 1) * 64 + lane];
                    acc = __builtin_amdgcn_mfma_f32_32x32x16_bf16(bh, ah, acc, 0, 0, 0);
                    acc = __builtin_amdgcn_mfma_f32_32x32x16_bf16(bl, ah, acc, 0, 0, 0);
                    acc = __builtin_amdgcn_mfma_f32_32x32x16_bf16(bh, al, acc, 0, 0, 0);
                }
            }

            float z8[8];
            #pragma unroll
            for (int r = 0; r < 8; ++r)
                z8[r] = softsign_f(acc[r]) * softsign_f(acc[r + 8]);

            float4 m0 = *(float4*)&sml[4 * kh];
            float4 m1 = *(float4*)&sml[8 + 4 * kh];
            float part = m0.x*z8[0] + m0.y*z8[1] + m0.z*z8[2] + m0.w*z8[3]
                       + m1.x*z8[4] + m1.y*z8[5] + m1.z*z8[6] + m1.w*z8[7];
            float tot = part + __shfl_xor(part, 32);

            if (li == 17) {
                if (kh == 0) out[j] = skipreg[tile] + tot;
            } else {
                if (kh == 0) skipreg[tile] += tot;

                float zo8[8];
                #pragma unroll
                for (int r = 0; r < 8; ++r) zo8[r] = __shfl_xor(z8[r], 32);

                unsigned int uh[4], ul[4];
                __builtin_memcpy(uh, &ah, 16);
                __builtin_memcpy(ul, &al, 16);
                unsigned int sh0 = kh ? uh[0] : uh[2], sh1 = kh ? uh[1] : uh[3];
                unsigned int sl0 = kh ? ul[0] : ul[2], sl1 = kh ? ul[1] : ul[3];
                unsigned int rh0 = (unsigned int)__shfl_xor((int)sh0, 32);
                unsigned int rh1 = (unsigned int)__shfl_xor((int)sh1, 32);
                unsigned int rl0 = (unsigned int)__shfl_xor((int)sl0, 32);
                unsigned int rl1 = (unsigned int)__shfl_xor((int)sl1, 32);
                unsigned int qh0 = kh ? uh[2] : uh[0], qh1 = kh ? uh[3] : uh[1];
                unsigned int ql0 = kh ? ul[2] : ul[0], ql1 = kh ? ul[3] : ul[1];
                unsigned int g1h0 = kh ? rh0 : qh0, g1h1 = kh ? rh1 : qh1;
                unsigned int g2h0 = kh ? qh0 : rh0, g2h1 = kh ? qh1 : rh1;
                unsigned int g1l0 = kh ? rl0 : ql0, g1l1 = kh ? rl1 : ql1;
                unsigned int g2l0 = kh ? ql0 : rl0, g2l1 = kh ? ql1 : rl1;

                float4 rb0 = *(float4*)&sml[16 + 4 * kh];
                float4 rb1 = *(float4*)&sml[24 + 4 * kh];
                float hn[8];
                hn[0] = bf2f(g1h0) + bf2f(g1l0) + rb0.x;
                hn[1] = bf2f(g1h0 >> 16) + bf2f(g1l0 >> 16) + rb0.y;
                hn[2] = bf2f(g1h1) + bf2f(g1l1) + rb0.z;
                hn[3] = bf2f(g1h1 >> 16) + bf2f(g1l1 >> 16) + rb0.w;
                hn[4] = bf2f(g2h0) + bf2f(g2l0) + rb1.x;
                hn[5] = bf2f(g2h0 >> 16) + bf2f(g2l0 >> 16) + rb1.y;
                hn[6] = bf2f(g2h1) + bf2f(g2l1) + rb1.z;
                hn[7] = bf2f(g2h1 >> 16) + bf2f(g2l1 >> 16) + rb1.w;

                #pragma unroll
                for (int i = 0; i < 16; ++i) {
                    const int idx = (i & 3) + 4 * (i >> 3);
                    const int ob  = (i >> 2) & 1;
                    const float zi = (ob == kh) ? z8[idx] : zo8[idx];
                    float4 wA = *(float4*)&rwl[i * 16 + 4 * kh];
                    float4 wB = *(float4*)&rwl[i * 16 + 8 + 4 * kh];
                    hn[0] += wA.x * zi; hn[1] += wA.y * zi;
                    hn[2] += wA.z * zi; hn[3] += wA.w * zi;
                    hn[4] += wB.x * zi; hn[5] += wB.y * zi;
                    hn[6] += wB.z * zi; hn[7] += wB.w * zi;
                }

                u64 s0, s1, s2, s3;
                {
                    unsigned short b0[4], b1[4], b2[4], b3[4];
                    #pragma unroll
                    for (int m = 0; m < 4; ++m) {
                        unsigned short u1 = f2bf(hn[m]);
                        b0[m] = u1; b2[m] = f2bf(hn[m] - bf2f(u1));
                        unsigned short u2 = f2bf(hn[4 + m]);
                        b1[m] = u2; b3[m] = f2bf(hn[4 + m] - bf2f(u2));
                    }
                    __builtin_memcpy(&s0, b0, 8);
                    __builtin_memcpy(&s1, b1, 8);
                    __builtin_memcpy(&s2, b2, 8);
                    __builtin_memcpy(&s3, b3, 8);
                }
                *(u64*)(hout_hi + (size_t)j * 16 + 4 * kh)     = s0;
                *(u64*)(hout_hi + (size_t)j * 16 + 8 + 4 * kh) = s1;
                *(u64*)(hout_lo + (size_t)j * 16 + 4 * kh)     = s2;
                *(u64*)(hout_lo + (size_t)j * 16 + 8 + 4 * kh) = s3;
                if (is_halo_prod) {
                    unsigned short* hb = halo_out
                        + (size_t)(wb >> 7) * 16384
                        + (size_t)((j & 32767) - 32256) * 32;
                    cohstore(hb + 4 * kh,          s0);
                    cohstore(hb + 8 + 4 * kh,      s1);
                    cohstore(hb + 16 + 4 * kh,     s2);
                    cohstore(hb + 16 + 8 + 4 * kh, s3);
                }
            }
        }

        if (li < 17) {
            __syncthreads();   // drains stores (L2 + halo) before flag
            if (td == 0) {
                __hip_atomic_store(&flags[li * NBLK + wb], 1u,
                                   __ATOMIC_RELAXED, __HIP_MEMORY_SCOPE_AGENT);
            }
        }
    }
}

extern "C" void kernel_launch(void* const* d_in, const int* in_sizes, int n_in,
                              void* d_out, int out_size, void* d_ws, size_t ws_size,
                              hipStream_t stream) {
    const float* x       = (const float*)d_in[0];
    const float* start_w = (const float*)d_in[1];
    const float* conv_w  = (const float*)d_in[2];
    const float* conv_b  = (const float*)d_in[3];
    const float* gate_w  = (const float*)d_in[4];
    const float* gate_b  = (const float*)d_in[5];
    const float* res_w   = (const float*)d_in[6];
    const float* res_b   = (const float*)d_in[7];
    const float* mixer_w = (const float*)d_in[8];
    float* out = (float*)d_out;

    float* ws = (float*)d_ws;
    unsigned short* bfrag = (unsigned short*)ws;            // 55296 ushorts
    float* fgbias = ws + 27648;                             // 576
    float* rwp    = fgbias + 576;                           // 4352
    float* e0f    = rwp + 4352;                             // 48
    float* e0g    = e0f + 48;                               // 48
    unsigned short* pbase = (unsigned short*)(e0g + 48);    // 2 plane-pairs
    unsigned short* halo  = pbase + 4 * PLANE;              // 2x8x512x32 ushorts
    unsigned int* flags = (unsigned int*)(halo + 262144);   // 17*1024
    (void)ws_size; (void)in_sizes; (void)n_in; (void)out_size;

    hipMemsetAsync(flags, 0, 17 * NBLK * sizeof(unsigned int), stream);

    pack_kernel<<<236, 256, 0, stream>>>(start_w, conv_w, gate_w, res_w,
                                         conv_b, gate_b,
                                         bfrag, fgbias, rwp, e0f, e0g);

    wavenet_fused<<<NBLK, 256, 0, stream>>>(
        x, start_w, conv_b, gate_b, res_b, mixer_w,
        bfrag, fgbias, rwp, e0f, e0g, pbase, halo, out, flags);
}